// Round 3
// baseline (18937.648 us; speedup 1.0000x reference)
//
#include <hip/hip_runtime.h>
#include <hip/hip_cooperative_groups.h>
#include <math.h>

namespace cg = cooperative_groups;

#define HH 512
#define VV 32000
#define BB 64
#define SS 64
#define TT 64
#define H3 1536

// workspace layout (float offsets)
#define WS_UK    0LL
#define WS_GIEMB (WS_UK + (long long)BB*SS*HH)        // Uk:    B*S*H
#define WS_HS    (WS_GIEMB + (long long)TT*BB*H3)     // GiEmb: T*B*3H
#define WS_QGH   (WS_HS + (long long)TT*BB*HH)        // Hs:    T*B*H (fp32)
#define WS_CTX   (WS_QGH + (long long)BB*2048)        // qbuf region
#define WS_GIC   (WS_CTX + (long long)BB*HH)          // ctx:   B*H
#define WS_WCAT  (WS_GIC + (long long)BB*H3)          // (gic region unused now)
#define WS_BCAT  (WS_WCAT + 2048LL*HH)                // Wcat:  2048*H
#define WS_HSBF  (WS_BCAT + 2048LL)                   // hsbf:  T*B*H bf16 (rows b*T+t)
#define WS_END   (WS_HSBF + (long long)TT*BB*HH/2)
// wbf (W_out bf16, 32000*512 shorts) aliases ws[0..8.192M) = Uk+GiEmb (dead after recurrence)

// output layout (floats)
#define OUT_HT  ((long long)BB*TT*VV)
#define OUT_ATT (OUT_HT + (long long)BB*HH)

typedef __attribute__((ext_vector_type(8))) short bf16x8;
typedef __attribute__((ext_vector_type(4))) float f32x4;

__device__ inline unsigned short f2b(float x) {
  unsigned u = __builtin_bit_cast(unsigned, x);
  unsigned r = (u + 0x7FFF + ((u >> 16) & 1)) >> 16;
  return (unsigned short)r;
}

// ---------------------------------------------------------------------------
// fp32 NT GEMM for precompute. ROWMAP: 0 = A row m; 1 = emb gather
// ---------------------------------------------------------------------------
template<int ROWMAP>
__global__ __launch_bounds__(256) void gemm_nt(const float* __restrict__ A, int lda,
    const float* __restrict__ Bm, int ldb, const float* __restrict__ bias,
    float* __restrict__ C, long long ldc, const int* __restrict__ tok)
{
  __shared__ float As[16][68];
  __shared__ float Bs[16][68];
  const int tid = threadIdx.x;
  const int tx = tid & 15, ty = tid >> 4;
  const int lr = tid & 63, lc = (tid >> 6) << 2;
  const int m0 = blockIdx.y * 64, n0 = blockIdx.x * 64;

  long long arow;
  {
    int m = m0 + lr;
    if (ROWMAP == 0) {
      arow = (long long)m * lda;
    } else {
      int t = m >> 6, b = m & 63;
      int tk = (t == 0) ? 0 : tok[b * TT + t - 1];
      arow = (long long)tk * lda;
    }
  }
  const float* Ap = A + arow;
  const float* Bp = Bm + (long long)(n0 + lr) * ldb;

  float acc[4][4];
  #pragma unroll
  for (int i = 0; i < 4; i++)
    #pragma unroll
    for (int j = 0; j < 4; j++) acc[i][j] = 0.f;

  for (int k0 = 0; k0 < HH; k0 += 16) {
    float4 av = *(const float4*)(Ap + k0 + lc);
    float4 bv = *(const float4*)(Bp + k0 + lc);
    __syncthreads();
    As[lc+0][lr] = av.x; As[lc+1][lr] = av.y; As[lc+2][lr] = av.z; As[lc+3][lr] = av.w;
    Bs[lc+0][lr] = bv.x; Bs[lc+1][lr] = bv.y; Bs[lc+2][lr] = bv.z; Bs[lc+3][lr] = bv.w;
    __syncthreads();
    #pragma unroll
    for (int kk = 0; kk < 16; kk++) {
      float a[4], b[4];
      #pragma unroll
      for (int i = 0; i < 4; i++) a[i] = As[kk][i*16 + ty];
      #pragma unroll
      for (int j = 0; j < 4; j++) b[j] = Bs[kk][j*16 + tx];
      #pragma unroll
      for (int i = 0; i < 4; i++)
        #pragma unroll
        for (int j = 0; j < 4; j++) acc[i][j] += a[i] * b[j];
    }
  }

  #pragma unroll
  for (int j = 0; j < 4; j++) {
    int col = n0 + j*16 + tx;
    float bb = bias ? bias[col] : 0.f;
    #pragma unroll
    for (int i = 0; i < 4; i++) {
      int row = m0 + i*16 + ty;
      C[(long long)row * ldc + col] = acc[i][j] + bb;
    }
  }
}

// ---------------------------------------------------------------------------
// One-time concat: Wcat = [Wa ; W_hh] (2048 x 512), bcat = [ba ; b_hh]
// ---------------------------------------------------------------------------
__global__ __launch_bounds__(256) void wcat_kernel(const float* __restrict__ Wa,
    const float* __restrict__ Whh, const float* __restrict__ ba,
    const float* __restrict__ bhh, float* __restrict__ Wcat, float* __restrict__ bcat)
{
  long long i = (long long)blockIdx.x * 256 + threadIdx.x;
  int j = (int)(i >> 9), k = (int)(i & 511);
  Wcat[i] = (j < HH) ? Wa[(long long)j*HH + k] : Whh[(long long)(j - HH)*HH + k];
  if (i < 2048) bcat[i] = (i < HH) ? ba[i] : bhh[i - HH];
}

// ---------------------------------------------------------------------------
// W_out (32000x512 fp32) -> bf16
// ---------------------------------------------------------------------------
__global__ __launch_bounds__(256) void cvt_wout_kernel(const float* __restrict__ in,
    unsigned short* __restrict__ outp)
{
  long long i = ((long long)blockIdx.x * 256 + threadIdx.x) * 8;
  float4 a = *(const float4*)(in + i);
  float4 b = *(const float4*)(in + i + 4);
  ushort4 lo = { f2b(a.x), f2b(a.y), f2b(a.z), f2b(a.w) };
  ushort4 hi = { f2b(b.x), f2b(b.y), f2b(b.z), f2b(b.w) };
  *(ushort4*)(outp + i)     = lo;
  *(ushort4*)(outp + i + 4) = hi;
}

// ---------------------------------------------------------------------------
// Persistent recurrence: 64 blocks x 1024 threads, cooperative.
// Block g owns: q-cols [g*8, g*8+8); gh/gic j-slice [g*8, g*8+8) (x3 gates);
// phase B handles batch b = g.
// ---------------------------------------------------------------------------
__global__ __launch_bounds__(1024) void recurrence_kernel(
    const float* __restrict__ eh, const float* __restrict__ wcat,
    const float* __restrict__ bcat, const float* __restrict__ W_ih,
    const float* __restrict__ giemb, const float* __restrict__ uk,
    const float* __restrict__ Va, const float* __restrict__ bvp,
    const float* __restrict__ enc, float* __restrict__ qbuf,
    float* __restrict__ ctxbuf, float* __restrict__ hs,
    unsigned short* __restrict__ hsbf, float* __restrict__ attn_out,
    float* __restrict__ out_ht)
{
  cg::grid_group grid = cg::this_grid();
  const int g = blockIdx.x;
  const int tid = threadIdx.x;

  __shared__ float gh_lds[64][24];        // gh for (b, gate*8+jj)
  __shared__ float qs[HH];                // q row for b=g (phase B)
  __shared__ float sc[SS];                // scores
  __shared__ float sw[SS];                // softmax weights
  __shared__ float part[2][512][3];       // phase C k-half partials

  const float bv0 = bvp[0];

  for (int t = 0; t < TT; ++t) {
    const float* hprev = (t == 0) ? eh : (hs + (long long)(t - 1) * BB * HH);

    // ---- Phase A: qgh columns ------------------------------------------
    {
      const int b = tid >> 4, c2 = tid & 15;
      // col indices c2 and c2+16 -> wcat rows
      int row0, row1;
      {
        int i = c2;   // 0..15: first 8 are q, next 8 are gh gate 0
        row0 = (i < 8) ? (g*8 + i) : (512 + 0*512 + g*8 + (i - 8));
        int i2 = c2 + 16;  // 16..31 -> gh gates 1,2
        int gate = (i2 - 8) >> 3, jj = (i2 - 8) & 7;
        row1 = 512 + gate*512 + g*8 + jj;
      }
      const float* hp = hprev + (long long)b * HH;
      const float* w0 = wcat + (long long)row0 * HH;
      const float* w1 = wcat + (long long)row1 * HH;
      float acc0 = 0.f, acc1 = 0.f;
      #pragma unroll 8
      for (int k = 0; k < HH; k += 4) {
        float4 h4 = *(const float4*)(hp + k);
        float4 a4 = *(const float4*)(w0 + k);
        float4 b4 = *(const float4*)(w1 + k);
        acc0 += h4.x*a4.x + h4.y*a4.y + h4.z*a4.z + h4.w*a4.w;
        acc1 += h4.x*b4.x + h4.y*b4.y + h4.z*b4.z + h4.w*b4.w;
      }
      acc0 += bcat[row0];
      acc1 += bcat[row1];
      if (c2 < 8) qbuf[(long long)b*HH + g*8 + c2] = acc0;
      else        gh_lds[b][c2 - 8] = acc0;
      gh_lds[b][c2 + 8] = acc1;    // (c2+16)-8 = c2+8, covers 8..23
    }
    grid.sync();

    // ---- Phase B: attention for b = g ----------------------------------
    {
      if (tid < HH) qs[tid] = qbuf[(long long)g*HH + tid];
      if (tid >= HH && tid < HH + HH) qs[0] = qs[0]; // no-op keep shape
      __syncthreads();

      // scores: s = tid>>4, 16 threads per s, 32 k each
      const int s = tid >> 4, sub = tid & 15;
      const float* ukp = uk + (long long)(g*SS + s) * HH + sub*32;
      const float* qp  = qs + sub*32;
      const float* vp  = Va + sub*32;
      float p = 0.f;
      #pragma unroll 8
      for (int k = 0; k < 32; k += 4) {
        float4 u4 = *(const float4*)(ukp + k);
        float4 q4 = *(const float4*)(qp + k);
        float4 v4 = *(const float4*)(vp + k);
        p += v4.x * tanhf(q4.x + u4.x) + v4.y * tanhf(q4.y + u4.y)
           + v4.z * tanhf(q4.z + u4.z) + v4.w * tanhf(q4.w + u4.w);
      }
      p += __shfl_xor(p, 1);
      p += __shfl_xor(p, 2);
      p += __shfl_xor(p, 4);
      p += __shfl_xor(p, 8);
      if (sub == 0) sc[s] = p + bv0;
      __syncthreads();

      if (tid < 64) {
        float x = sc[tid], mx = x;
        #pragma unroll
        for (int off = 32; off; off >>= 1) mx = fmaxf(mx, __shfl_xor(mx, off));
        float e = expf(x - mx), sm = e;
        #pragma unroll
        for (int off = 32; off; off >>= 1) sm += __shfl_xor(sm, off);
        float w = e / sm;
        sw[tid] = w;
        attn_out[((long long)g*TT + t)*SS + tid] = w;
      }
      __syncthreads();

      if (tid < HH) {
        float a0 = 0.f;
        const float* ep = enc + (long long)g*SS*HH + tid;
        #pragma unroll 8
        for (int s2 = 0; s2 < SS; ++s2) a0 += sw[s2] * ep[(long long)s2*HH];
        ctxbuf[(long long)g*HH + tid] = a0;
      }
    }
    grid.sync();

    // ---- Phase C: gic j-slice + gates ----------------------------------
    {
      const int p = tid & 511, half = tid >> 9;
      const int b = p >> 3, jj = p & 7;
      const float* cp = ctxbuf + (long long)b*HH + half*256;
      #pragma unroll
      for (int gate = 0; gate < 3; ++gate) {
        const float* wp = W_ih + (long long)(gate*512 + g*8 + jj) * 1024 + 512 + half*256;
        float acc = 0.f;
        #pragma unroll 8
        for (int k = 0; k < 256; k += 4) {
          float4 c4 = *(const float4*)(cp + k);
          float4 w4 = *(const float4*)(wp + k);
          acc += c4.x*w4.x + c4.y*w4.y + c4.z*w4.z + c4.w*w4.w;
        }
        part[half][p][gate] = acc;
      }
      __syncthreads();

      if (tid < 512) {
        const int j = g*8 + jj;
        const long long gie = ((long long)t*BB + b) * H3;
        float gic_r = part[0][p][0] + part[1][p][0];
        float gic_z = part[0][p][1] + part[1][p][1];
        float gic_n = part[0][p][2] + part[1][p][2];
        float gi_r = giemb[gie + j]        + gic_r;
        float gi_z = giemb[gie + 512 + j]  + gic_z;
        float gi_n = giemb[gie + 1024 + j] + gic_n;
        float gh_r = gh_lds[b][jj];
        float gh_z = gh_lds[b][8 + jj];
        float gh_n = gh_lds[b][16 + jj];
        float r = 1.f / (1.f + expf(-(gi_r + gh_r)));
        float z = 1.f / (1.f + expf(-(gi_z + gh_z)));
        float n = tanhf(gi_n + r * gh_n);
        float hp = hprev[(long long)b*HH + j];
        float hn = (1.f - z) * n + z * hp;
        hs[((long long)t*BB + b)*HH + j] = hn;
        hsbf[((long long)b*TT + t)*HH + j] = f2b(hn);
        if (t == TT - 1) out_ht[(long long)b*HH + j] = hn;
      }
    }
    grid.sync();
  }
}

// ---------------------------------------------------------------------------
// Output projection: bf16 MFMA 16x16x32, 128x128 tile, BK=32, 4 waves.
// ---------------------------------------------------------------------------
__global__ __launch_bounds__(256) void gemm_out_mfma(const unsigned short* __restrict__ A,
    const unsigned short* __restrict__ Bw, const float* __restrict__ bias,
    float* __restrict__ C)
{
  __shared__ unsigned short As[128*32];
  __shared__ unsigned short Bs[128*32];
  const int tid = threadIdx.x;
  const int w = tid >> 6, l = tid & 63;
  const int m0 = blockIdx.y * 128, n0 = blockIdx.x * 128;
  const int wr = w >> 1, wc = w & 1;

  f32x4 acc[4][4];
  #pragma unroll
  for (int i = 0; i < 4; i++)
    #pragma unroll
    for (int j = 0; j < 4; j++) acc[i][j] = (f32x4){0.f, 0.f, 0.f, 0.f};

  const int srow = l >> 2;
  const int scol = (l & 3) * 8;

  for (int k0 = 0; k0 < HH; k0 += 32) {
    __syncthreads();
    #pragma unroll
    for (int q = 0; q < 2; ++q) {
      int r = w*32 + q*16 + srow;
      __builtin_amdgcn_global_load_lds(
          (const __attribute__((address_space(1))) void*)(A + (long long)(m0 + r)*HH + k0 + scol),
          (__attribute__((address_space(3))) void*)(As + r*32 + scol), 16, 0, 0);
      __builtin_amdgcn_global_load_lds(
          (const __attribute__((address_space(1))) void*)(Bw + (long long)(n0 + r)*HH + k0 + scol),
          (__attribute__((address_space(3))) void*)(Bs + r*32 + scol), 16, 0, 0);
    }
    __syncthreads();

    bf16x8 a[4], b[4];
    #pragma unroll
    for (int mi = 0; mi < 4; mi++)
      a[mi] = *(const bf16x8*)&As[(wr*64 + mi*16 + (l & 15))*32 + (l >> 4)*8];
    #pragma unroll
    for (int ni = 0; ni < 4; ni++)
      b[ni] = *(const bf16x8*)&Bs[(wc*64 + ni*16 + (l & 15))*32 + (l >> 4)*8];
    #pragma unroll
    for (int mi = 0; mi < 4; mi++)
      #pragma unroll
      for (int ni = 0; ni < 4; ni++)
        acc[mi][ni] = __builtin_amdgcn_mfma_f32_16x16x32_bf16(a[mi], b[ni], acc[mi][ni], 0, 0, 0);
  }

  #pragma unroll
  for (int mi = 0; mi < 4; mi++) {
    #pragma unroll
    for (int ni = 0; ni < 4; ni++) {
      int col = n0 + wc*64 + ni*16 + (l & 15);
      float bb = bias[col];
      #pragma unroll
      for (int r2 = 0; r2 < 4; r2++) {
        int row = m0 + wr*64 + mi*16 + (l >> 4)*4 + r2;
        C[(long long)row*VV + col] = acc[mi][ni][r2] + bb;
      }
    }
  }
}

// ---------------------------------------------------------------------------
// In-place log-softmax over rows of V=32000
// ---------------------------------------------------------------------------
__global__ __launch_bounds__(256) void logsoftmax_kernel(float* __restrict__ lp)
{
  float* p = lp + (long long)blockIdx.x * VV;
  const int tid = threadIdx.x;
  float m = -1e30f, s = 0.f;
  for (int v = tid; v < VV; v += 256) {
    float x = p[v];
    if (x > m) { s = s * expf(m - x) + 1.f; m = x; }
    else       { s += expf(x - m); }
  }
  __shared__ float rm[256], rs[256];
  rm[tid] = m; rs[tid] = s;
  __syncthreads();
  for (int off = 128; off; off >>= 1) {
    if (tid < off) {
      float m2 = rm[tid + off], s2 = rs[tid + off];
      float mm = fmaxf(rm[tid], m2);
      rs[tid] = rs[tid] * expf(rm[tid] - mm) + s2 * expf(m2 - mm);
      rm[tid] = mm;
    }
    __syncthreads();
  }
  const float L = rm[0] + logf(rs[0]);
  for (int v = tid; v < VV; v += 256) p[v] -= L;
}

// ---------------------------------------------------------------------------
extern "C" void kernel_launch(void* const* d_in, const int* in_sizes, int n_in,
                              void* d_out, int out_size, void* d_ws, size_t ws_size,
                              hipStream_t stream)
{
  const float* enc   = (const float*)d_in[0];
  const float* eh    = (const float*)d_in[1];
  const int*   tgt   = (const int*)  d_in[2];
  const float* emb   = (const float*)d_in[3];
  const float* Wa    = (const float*)d_in[4];
  const float* ba    = (const float*)d_in[5];
  const float* Ua    = (const float*)d_in[6];
  const float* bu    = (const float*)d_in[7];
  const float* Va    = (const float*)d_in[8];
  const float* bvp   = (const float*)d_in[9];
  const float* W_ih  = (const float*)d_in[10];
  const float* W_hh  = (const float*)d_in[11];
  const float* b_ih  = (const float*)d_in[12];
  const float* b_hh  = (const float*)d_in[13];
  const float* W_out = (const float*)d_in[14];
  const float* b_out = (const float*)d_in[15];

  float* out = (float*)d_out;
  float* ws  = (float*)d_ws;

  float* uk    = ws + WS_UK;
  float* gie   = ws + WS_GIEMB;
  float* hs    = ws + WS_HS;
  float* qbuf  = ws + WS_QGH;
  float* ctxb  = ws + WS_CTX;
  float* wcat  = ws + WS_WCAT;
  float* bcat  = ws + WS_BCAT;
  unsigned short* hsbf = (unsigned short*)(ws + WS_HSBF);
  unsigned short* wbf  = (unsigned short*)ws;   // aliases Uk+GiEmb after recurrence

  wcat_kernel<<<dim3(4096), dim3(256), 0, stream>>>(Wa, W_hh, ba, b_hh, wcat, bcat);

  // Uk = enc @ Ua^T + bu
  gemm_nt<0><<<dim3(8, 64), dim3(256), 0, stream>>>(enc, HH, Ua, HH, bu, uk, (long long)HH, nullptr);

  // GiEmb = emb[tok] @ W_ih[:, :H]^T + b_ih
  gemm_nt<1><<<dim3(24, 64), dim3(256), 0, stream>>>(emb, HH, W_ih, 2*HH, b_ih, gie, (long long)H3, tgt);

  // Persistent recurrence (cooperative): all 64 steps in one kernel
  {
    float* attn_out = out + OUT_ATT;
    float* out_ht   = out + OUT_HT;
    void* kargs[] = {
      (void*)&eh, (void*)&wcat, (void*)&bcat, (void*)&W_ih, (void*)&gie,
      (void*)&uk, (void*)&Va, (void*)&bvp, (void*)&enc, (void*)&qbuf,
      (void*)&ctxb, (void*)&hs, (void*)&hsbf, (void*)&attn_out, (void*)&out_ht
    };
    hipLaunchCooperativeKernel((void*)recurrence_kernel, dim3(64), dim3(1024),
                               kargs, 0, stream);
  }

  // W_out -> bf16 (into dead Uk/GiEmb region)
  cvt_wout_kernel<<<dim3(8000), dim3(256), 0, stream>>>(W_out, wbf);

  // logits = hsbf @ wbf^T + b_out
  gemm_out_mfma<<<dim3(250, 32), dim3(256), 0, stream>>>(hsbf, wbf, b_out, out);

  // in-place log-softmax
  logsoftmax_kernel<<<dim3(4096), dim3(256), 0, stream>>>(out);
}

// Round 4
// 8734.341 us; speedup vs baseline: 2.1682x; 2.1682x over previous
//
#include <hip/hip_runtime.h>
#include <hip/hip_cooperative_groups.h>
#include <math.h>

namespace cg = cooperative_groups;

#define HH 512
#define VV 32000
#define BB 64
#define SS 64
#define TT 64
#define H3 1536

// ---- workspace layout (float offsets) ----
#define WS_GIEMB 0LL                                   // 4096*1536 f32
#define WS_UKBF  (WS_GIEMB + 6291456LL)                // 2M ushort = 1M f
#define WS_ENCBF (WS_UKBF + 1048576LL)                 // 2M ushort = 1M f
#define WS_WCATBF (WS_ENCBF + 1048576LL)               // 2048*512 us = 512K f
#define WS_WIHCBF (WS_WCATBF + 524288LL)               // 1536*512 us = 384K f
#define WS_BCAT  (WS_WIHCBF + 393216LL)                // 2048 f
#define WS_QBUF  (WS_BCAT + 2048LL)                    // 64*512 f
#define WS_GHT   (WS_QBUF + 32768LL)                   // 1536*64 f
#define WS_CTXBF (WS_GHT + 98304LL)                    // 64*512 us
#define WS_HSBF  (WS_CTXBF + 16384LL)                  // 64*512 us
#define WS_HSALL (WS_HSBF + 16384LL)                   // 4096*512 us = 1M f
// total ~10.5M floats (~42MB). wbf (32000*512 us = 8.192M f) aliases ws[0..8.388M)
// = GIEMB+UKBF+ENCBF, all dead after the recurrence.

// output layout (floats)
#define OUT_HT  ((long long)BB*TT*VV)
#define OUT_ATT (OUT_HT + (long long)BB*HH)

// recurrence role block ranges
#define RB_Q0   64
#define RB_GH0  96
#define RB_GIC0 192

typedef __attribute__((ext_vector_type(8))) short bf16x8;
typedef __attribute__((ext_vector_type(4))) float f32x4;

__device__ inline unsigned short f2b(float x) {
  unsigned u = __builtin_bit_cast(unsigned, x);
  unsigned r = (u + 0x7FFF + ((u >> 16) & 1)) >> 16;
  return (unsigned short)r;
}
__device__ inline float bc(unsigned u) { return __builtin_bit_cast(float, u); }
__device__ inline float frcp(float x) { return __builtin_amdgcn_rcpf(x); }
__device__ inline float tanh_fast(float x) { return 1.f - 2.f * frcp(__expf(2.f * x) + 1.f); }
__device__ inline float sigm(float x) { return frcp(1.f + __expf(-x)); }

// 2 bf16 pairs MAC into fp32 acc
__device__ inline float mac2(unsigned ha, unsigned wa, float acc) {
  acc = fmaf(bc(ha << 16), bc(wa << 16), acc);
  return fmaf(bc(ha & 0xffff0000u), bc(wa & 0xffff0000u), acc);
}

// dot of 512 bf16: g = global row (linear), w = LDS row base with chunk-XOR swizzle xm
__device__ inline float dot512_swz(const unsigned short* __restrict__ g,
                                   const unsigned short* __restrict__ w, int xm) {
  float acc = 0.f;
  #pragma unroll 8
  for (int c = 0; c < 64; ++c) {
    uint4 av = *(const uint4*)(g + c * 8);
    uint4 bv = *(const uint4*)(w + ((c ^ xm) << 3));
    acc = mac2(av.x, bv.x, acc);
    acc = mac2(av.y, bv.y, acc);
    acc = mac2(av.z, bv.z, acc);
    acc = mac2(av.w, bv.w, acc);
  }
  return acc;
}

// ---------------------------------------------------------------------------
// fp32 NT GEMM for precompute. ROWMAP: 0 = A row m; 1 = emb gather.
// OUTBF: 1 -> write bf16 C.
// ---------------------------------------------------------------------------
template<int ROWMAP, int OUTBF>
__global__ __launch_bounds__(256) void gemm_nt(const float* __restrict__ A, int lda,
    const float* __restrict__ Bm, int ldb, const float* __restrict__ bias,
    void* __restrict__ Cv, long long ldc, const int* __restrict__ tok)
{
  __shared__ float As[16][68];
  __shared__ float Bs[16][68];
  const int tid = threadIdx.x;
  const int tx = tid & 15, ty = tid >> 4;
  const int lr = tid & 63, lc = (tid >> 6) << 2;
  const int m0 = blockIdx.y * 64, n0 = blockIdx.x * 64;

  long long arow;
  {
    int m = m0 + lr;
    if (ROWMAP == 0) {
      arow = (long long)m * lda;
    } else {
      int t = m >> 6, b = m & 63;
      int tk = (t == 0) ? 0 : tok[b * TT + t - 1];
      arow = (long long)tk * lda;
    }
  }
  const float* Ap = A + arow;
  const float* Bp = Bm + (long long)(n0 + lr) * ldb;

  float acc[4][4];
  #pragma unroll
  for (int i = 0; i < 4; i++)
    #pragma unroll
    for (int j = 0; j < 4; j++) acc[i][j] = 0.f;

  for (int k0 = 0; k0 < HH; k0 += 16) {
    float4 av = *(const float4*)(Ap + k0 + lc);
    float4 bv = *(const float4*)(Bp + k0 + lc);
    __syncthreads();
    As[lc+0][lr] = av.x; As[lc+1][lr] = av.y; As[lc+2][lr] = av.z; As[lc+3][lr] = av.w;
    Bs[lc+0][lr] = bv.x; Bs[lc+1][lr] = bv.y; Bs[lc+2][lr] = bv.z; Bs[lc+3][lr] = bv.w;
    __syncthreads();
    #pragma unroll
    for (int kk = 0; kk < 16; kk++) {
      float a[4], b[4];
      #pragma unroll
      for (int i = 0; i < 4; i++) a[i] = As[kk][i*16 + ty];
      #pragma unroll
      for (int j = 0; j < 4; j++) b[j] = Bs[kk][j*16 + tx];
      #pragma unroll
      for (int i = 0; i < 4; i++)
        #pragma unroll
        for (int j = 0; j < 4; j++) acc[i][j] += a[i] * b[j];
    }
  }

  #pragma unroll
  for (int j = 0; j < 4; j++) {
    int col = n0 + j*16 + tx;
    float bb = bias ? bias[col] : 0.f;
    #pragma unroll
    for (int i = 0; i < 4; i++) {
      int row = m0 + i*16 + ty;
      float v = acc[i][j] + bb;
      if (OUTBF) ((unsigned short*)Cv)[(long long)row * ldc + col] = f2b(v);
      else       ((float*)Cv)[(long long)row * ldc + col] = v;
    }
  }
}

// ---------------------------------------------------------------------------
// prep kernels
// ---------------------------------------------------------------------------
__global__ __launch_bounds__(256) void build_wcat_kernel(const float* __restrict__ Wa,
    const float* __restrict__ Whh, const float* __restrict__ ba,
    const float* __restrict__ bhh, unsigned short* __restrict__ wcatbf,
    float* __restrict__ bcat)
{
  long long i = (long long)blockIdx.x * 256 + threadIdx.x;   // 2048*512
  int j = (int)(i >> 9), k = (int)(i & 511);
  float v = (j < HH) ? Wa[(long long)j*HH + k] : Whh[(long long)(j - HH)*HH + k];
  wcatbf[i] = f2b(v);
  if (i < 2048) bcat[i] = (i < HH) ? ba[i] : bhh[i - HH];
}

__global__ __launch_bounds__(256) void build_wihc_kernel(const float* __restrict__ W_ih,
    unsigned short* __restrict__ wihcbf)
{
  long long i = (long long)blockIdx.x * 256 + threadIdx.x;   // 1536*512
  int j = (int)(i >> 9), k = (int)(i & 511);
  wihcbf[i] = f2b(W_ih[(long long)j*1024 + 512 + k]);
}

__global__ __launch_bounds__(256) void cvt_f2b_kernel(const float* __restrict__ in,
    unsigned short* __restrict__ outp, long long n)
{
  long long i = ((long long)blockIdx.x * 256 + threadIdx.x) * 4;
  if (i >= n) return;
  float4 v = *(const float4*)(in + i);
  ushort4 r = { f2b(v.x), f2b(v.y), f2b(v.z), f2b(v.w) };
  *(ushort4*)(outp + i) = r;
}

// ---------------------------------------------------------------------------
// Persistent role-specialized recurrence. 256 blocks x 1024 threads.
// blocks [0,64): attention (batch b = bid)
// blocks [64,96): q cols (16 each);  [96,192): gh cols (16 each)
// blocks [192,256): gic j-slice (8 j -> 24 cols) + gates; h-slice lives in LDS
// ---------------------------------------------------------------------------
__global__ __launch_bounds__(1024) void recurrence_coop(
    const float* __restrict__ eh, const unsigned short* __restrict__ wcatbf,
    const float* __restrict__ bcat, const unsigned short* __restrict__ wihcbf,
    const float* __restrict__ giemb, const unsigned short* __restrict__ ukbf,
    const unsigned short* __restrict__ encbf, const float* __restrict__ Va,
    const float* __restrict__ bvp, float* __restrict__ qbuf,
    float* __restrict__ ghT, unsigned short* __restrict__ ctxbf,
    unsigned short* __restrict__ hsbf, unsigned short* __restrict__ hsall,
    float* __restrict__ attn_out, float* __restrict__ out_ht)
{
  cg::grid_group grid = cg::this_grid();
  const int bid = blockIdx.x, tid = threadIdx.x;

  __shared__ __align__(16) char smem[39424];
  unsigned short* wl = (unsigned short*)smem;            // up to 24 rows x 512 (swizzled)
  // role float regions
  float* qfl  = (float*)(smem + 16*512*2);               // q/gh: bias[16]
  float* gie  = (float*)(smem + 24*512*2);               // gic: [64][24]
  float* gicv = gie + 1536;                              // gic: [64][24]
  float* hsl  = gicv + 1536;                             // gic: [64][8]
  float* qs   = (float*)smem;                            // attn: [512]
  float* va   = qs + 512;                                // attn: [512]
  float* sc   = va + 512;                                // attn: [64]
  float* sw   = sc + 64;                                 // attn: [64]
  float* ctmp = sw + 64;                                 // attn: [4][512]

  const float bv0 = bvp[0];

  // ---- prologue: pin LDS ----
  if (bid >= RB_Q0 && bid < RB_GIC0) {                   // q or gh
    const int R0 = (bid < RB_GH0) ? (bid - RB_Q0) * 16 : 512 + (bid - RB_GH0) * 16;
    for (int i = tid; i < 16*512; i += 1024) {
      int u = i >> 9, k = i & 511;
      int idx = (u << 9) | ((((k >> 3) ^ (u & 7)) << 3) | (k & 7));
      wl[idx] = wcatbf[(long long)R0*512 + i];
    }
    if (tid < 16) qfl[tid] = bcat[R0 + tid];
  } else if (bid >= RB_GIC0) {                           // gic
    const int j0 = (bid - RB_GIC0) * 8;
    for (int i = tid; i < 24*512; i += 1024) {
      int c = i >> 9, k = i & 511;
      int row = (c >> 3) * 512 + j0 + (c & 7);
      int idx = (c << 9) | ((((k >> 3) ^ (c & 7)) << 3) | (k & 7));
      wl[idx] = wihcbf[(long long)row*512 + k];
    }
    if (tid < 512) { int b = tid >> 3, jj = tid & 7; hsl[b*8 + jj] = eh[b*512 + j0 + jj]; }
  } else {                                               // attn
    for (int i = tid; i < 512; i += 1024) va[i] = Va[i];
  }

  for (int t = 0; t < TT; ++t) {
    grid.sync();   // h(t-1) visible; also covers prologue on t=0

    // ================= window A =================
    if (bid >= RB_Q0 && bid < RB_GH0) {
      // q = h @ Wa^T + ba  (16 cols)
      const int b = tid >> 4, u = tid & 15;
      const int col = (bid - RB_Q0) * 16 + u;
      float acc = dot512_swz(hsbf + b*512, wl + (u << 9), u & 7) + qfl[u];
      qbuf[b*512 + col] = acc;
    } else if (bid >= RB_GIC0) {
      // prefetch giemb[t] slice
      const int j0 = (bid - RB_GIC0) * 8;
      for (int i = tid; i < 2048; i += 1024) {
        int b = i >> 5, c = i & 31;
        if (c < 24)
          gie[b*24 + c] = giemb[((long long)t*BB + b)*H3 + (c >> 3)*512 + j0 + (c & 7)];
      }
    }

    grid.sync();   // q ready

    // ================= window B =================
    if (bid < RB_Q0) {
      // ---- attention for batch b = bid ----
      if (tid < 512) qs[tid] = qbuf[bid*512 + tid];
      __syncthreads();
      {
        const int s = tid >> 4, sub = tid & 15;
        const unsigned short* up = ukbf + ((long long)(bid*SS + s) << 9) + sub*32;
        const float* qp = qs + sub*32;
        const float* vp = va + sub*32;
        float p = 0.f;
        #pragma unroll
        for (int kk = 0; kk < 32; kk += 4) {
          uint2 uv = *(const uint2*)(up + kk);
          p = fmaf(vp[kk+0], tanh_fast(qp[kk+0] + bc(uv.x << 16)), p);
          p = fmaf(vp[kk+1], tanh_fast(qp[kk+1] + bc(uv.x & 0xffff0000u)), p);
          p = fmaf(vp[kk+2], tanh_fast(qp[kk+2] + bc(uv.y << 16)), p);
          p = fmaf(vp[kk+3], tanh_fast(qp[kk+3] + bc(uv.y & 0xffff0000u)), p);
        }
        p += __shfl_xor(p, 1);
        p += __shfl_xor(p, 2);
        p += __shfl_xor(p, 4);
        p += __shfl_xor(p, 8);
        if (sub == 0) sc[s] = p + bv0;
      }
      __syncthreads();
      if (tid < 64) {
        float x = sc[tid], mx = x;
        #pragma unroll
        for (int off = 32; off; off >>= 1) mx = fmaxf(mx, __shfl_xor(mx, off));
        float e = __expf(x - mx), sm = e;
        #pragma unroll
        for (int off = 32; off; off >>= 1) sm += __shfl_xor(sm, off);
        float w = e * frcp(sm);
        sw[tid] = w;
        attn_out[((long long)bid*TT + t)*SS + tid] = w;
      }
      __syncthreads();
      {
        const int p2 = tid & 255, grp = tid >> 8;
        float a0 = 0.f, a1 = 0.f;
        const int sbase = grp * 16;
        #pragma unroll 4
        for (int si = 0; si < 16; ++si) {
          unsigned ev = *(const unsigned*)(encbf + ((long long)(bid*SS + sbase + si) << 9) + 2*p2);
          float w = sw[sbase + si];
          a0 = fmaf(bc(ev << 16), w, a0);
          a1 = fmaf(bc(ev & 0xffff0000u), w, a1);
        }
        ctmp[grp*512 + 2*p2]     = a0;
        ctmp[grp*512 + 2*p2 + 1] = a1;
      }
      __syncthreads();
      if (tid < 512) {
        float c = ctmp[tid] + ctmp[512 + tid] + ctmp[1024 + tid] + ctmp[1536 + tid];
        ctxbf[bid*512 + tid] = f2b(c);
      }
    } else if (bid >= RB_GH0 && bid < RB_GIC0) {
      // ---- gh = h @ W_hh^T + b_hh (16 cols), transposed store ----
      const int b = tid >> 4, u = tid & 15;
      const int col = (bid - RB_GH0) * 16 + u;
      float acc = dot512_swz(hsbf + b*512, wl + (u << 9), u & 7) + qfl[u];
      ghT[(long long)col*64 + b] = acc;
    }

    grid.sync();   // ctx, gh ready

    // ================= window C =================
    if (bid >= RB_GIC0) {
      const int j0 = (bid - RB_GIC0) * 8;
      const int b = tid >> 4, u = tid & 15;
      for (int c = u; c < 24; c += 16)
        gicv[b*24 + c] = dot512_swz(ctxbf + b*512, wl + (c << 9), c & 7);
      __syncthreads();
      if (tid < 512) {
        const int b2 = tid >> 3, jj = tid & 7, j = j0 + jj;
        float gr = gie[b2*24 + jj]      + gicv[b2*24 + jj];
        float gz = gie[b2*24 + 8 + jj]  + gicv[b2*24 + 8 + jj];
        float gn = gie[b2*24 + 16 + jj] + gicv[b2*24 + 16 + jj];
        float hr = ghT[(long long)j*64 + b2];
        float hz = ghT[(long long)(512 + j)*64 + b2];
        float hnn = ghT[(long long)(1024 + j)*64 + b2];
        float r = sigm(gr + hr);
        float z = sigm(gz + hz);
        float n = tanh_fast(gn + r * hnn);
        float hp = hsl[b2*8 + jj];
        float h = (1.f - z) * n + z * hp;
        hsl[b2*8 + jj] = h;
        unsigned short hb = f2b(h);
        hsbf[b2*512 + j] = hb;
        hsall[((long long)b2*TT + t)*512 + j] = hb;
        if (t == TT - 1) out_ht[b2*512 + j] = h;
      }
    }
  }
}

// ---------------------------------------------------------------------------
// Output projection: bf16 MFMA 16x16x32, 128x128 tile, BK=32, 4 waves.
// ---------------------------------------------------------------------------
__global__ __launch_bounds__(256) void gemm_out_mfma(const unsigned short* __restrict__ A,
    const unsigned short* __restrict__ Bw, const float* __restrict__ bias,
    float* __restrict__ C)
{
  __shared__ unsigned short As[128*32];
  __shared__ unsigned short Bs[128*32];
  const int tid = threadIdx.x;
  const int w = tid >> 6, l = tid & 63;
  const int m0 = blockIdx.y * 128, n0 = blockIdx.x * 128;
  const int wr = w >> 1, wc = w & 1;

  f32x4 acc[4][4];
  #pragma unroll
  for (int i = 0; i < 4; i++)
    #pragma unroll
    for (int j = 0; j < 4; j++) acc[i][j] = (f32x4){0.f, 0.f, 0.f, 0.f};

  const int srow = l >> 2;
  const int scol = (l & 3) * 8;

  for (int k0 = 0; k0 < HH; k0 += 32) {
    __syncthreads();
    #pragma unroll
    for (int q = 0; q < 2; ++q) {
      int r = w*32 + q*16 + srow;
      __builtin_amdgcn_global_load_lds(
          (const __attribute__((address_space(1))) void*)(A + (long long)(m0 + r)*HH + k0 + scol),
          (__attribute__((address_space(3))) void*)(As + r*32 + scol), 16, 0, 0);
      __builtin_amdgcn_global_load_lds(
          (const __attribute__((address_space(1))) void*)(Bw + (long long)(n0 + r)*HH + k0 + scol),
          (__attribute__((address_space(3))) void*)(Bs + r*32 + scol), 16, 0, 0);
    }
    __syncthreads();

    bf16x8 a[4], b[4];
    #pragma unroll
    for (int mi = 0; mi < 4; mi++)
      a[mi] = *(const bf16x8*)&As[(wr*64 + mi*16 + (l & 15))*32 + (l >> 4)*8];
    #pragma unroll
    for (int ni = 0; ni < 4; ni++)
      b[ni] = *(const bf16x8*)&Bs[(wc*64 + ni*16 + (l & 15))*32 + (l >> 4)*8];
    #pragma unroll
    for (int mi = 0; mi < 4; mi++)
      #pragma unroll
      for (int ni = 0; ni < 4; ni++)
        acc[mi][ni] = __builtin_amdgcn_mfma_f32_16x16x32_bf16(a[mi], b[ni], acc[mi][ni], 0, 0, 0);
  }

  #pragma unroll
  for (int mi = 0; mi < 4; mi++) {
    #pragma unroll
    for (int ni = 0; ni < 4; ni++) {
      int col = n0 + wc*64 + ni*16 + (l & 15);
      float bb = bias[col];
      #pragma unroll
      for (int r2 = 0; r2 < 4; r2++) {
        int row = m0 + wr*64 + mi*16 + (l >> 4)*4 + r2;
        C[(long long)row*VV + col] = acc[mi][ni][r2] + bb;
      }
    }
  }
}

// ---------------------------------------------------------------------------
// In-place log-softmax over rows of V=32000
// ---------------------------------------------------------------------------
__global__ __launch_bounds__(256) void logsoftmax_kernel(float* __restrict__ lp)
{
  float* p = lp + (long long)blockIdx.x * VV;
  const int tid = threadIdx.x;
  float m = -1e30f, s = 0.f;
  for (int v = tid; v < VV; v += 256) {
    float x = p[v];
    if (x > m) { s = s * __expf(m - x) + 1.f; m = x; }
    else       { s += __expf(x - m); }
  }
  __shared__ float rm[256], rs[256];
  rm[tid] = m; rs[tid] = s;
  __syncthreads();
  for (int off = 128; off; off >>= 1) {
    if (tid < off) {
      float m2 = rm[tid + off], s2 = rs[tid + off];
      float mm = fmaxf(rm[tid], m2);
      rs[tid] = rs[tid] * __expf(rm[tid] - mm) + s2 * __expf(m2 - mm);
      rm[tid] = mm;
    }
    __syncthreads();
  }
  const float L = rm[0] + logf(rs[0]);
  for (int v = tid; v < VV; v += 256) p[v] -= L;
}

// ---------------------------------------------------------------------------
extern "C" void kernel_launch(void* const* d_in, const int* in_sizes, int n_in,
                              void* d_out, int out_size, void* d_ws, size_t ws_size,
                              hipStream_t stream)
{
  const float* enc   = (const float*)d_in[0];
  const float* eh    = (const float*)d_in[1];
  const int*   tgt   = (const int*)  d_in[2];
  const float* emb   = (const float*)d_in[3];
  const float* Wa    = (const float*)d_in[4];
  const float* ba    = (const float*)d_in[5];
  const float* Ua    = (const float*)d_in[6];
  const float* bu    = (const float*)d_in[7];
  const float* Va    = (const float*)d_in[8];
  const float* bvp   = (const float*)d_in[9];
  const float* W_ih  = (const float*)d_in[10];
  const float* W_hh  = (const float*)d_in[11];
  const float* b_ih  = (const float*)d_in[12];
  const float* b_hh  = (const float*)d_in[13];
  const float* W_out = (const float*)d_in[14];
  const float* b_out = (const float*)d_in[15];

  float* out = (float*)d_out;
  float* ws  = (float*)d_ws;

  float* giemb = ws + WS_GIEMB;
  unsigned short* ukbf   = (unsigned short*)(ws + WS_UKBF);
  unsigned short* encbf  = (unsigned short*)(ws + WS_ENCBF);
  unsigned short* wcatbf = (unsigned short*)(ws + WS_WCATBF);
  unsigned short* wihcbf = (unsigned short*)(ws + WS_WIHCBF);
  float* bcat  = ws + WS_BCAT;
  float* qbuf  = ws + WS_QBUF;
  float* ghT   = ws + WS_GHT;
  unsigned short* ctxbf = (unsigned short*)(ws + WS_CTXBF);
  unsigned short* hsbf  = (unsigned short*)(ws + WS_HSBF);
  unsigned short* hsall = (unsigned short*)(ws + WS_HSALL);
  unsigned short* wbf   = (unsigned short*)ws;   // aliases giemb+ukbf+encbf post-recurrence

  // ---- prep (all independent, stream-ordered) ----
  build_wcat_kernel<<<dim3(4096), dim3(256), 0, stream>>>(Wa, W_hh, ba, b_hh, wcatbf, bcat);
  build_wihc_kernel<<<dim3(3072), dim3(256), 0, stream>>>(W_ih, wihcbf);
  {
    long long n = (long long)BB*SS*HH;  // enc -> bf16
    cvt_f2b_kernel<<<dim3((unsigned)((n/4 + 255)/256)), dim3(256), 0, stream>>>(enc, encbf, n);
  }
  {
    long long n = (long long)BB*HH;     // eh -> hsbf (initial h)
    cvt_f2b_kernel<<<dim3((unsigned)((n/4 + 255)/256)), dim3(256), 0, stream>>>(eh, hsbf, n);
  }
  // ukbf = bf16(enc @ Ua^T + bu)
  gemm_nt<0,1><<<dim3(8, 64), dim3(256), 0, stream>>>(enc, HH, Ua, HH, bu, (void*)ukbf, (long long)HH, nullptr);
  // giemb = emb[tok] @ W_ih[:, :H]^T + b_ih  (fp32)
  gemm_nt<1,0><<<dim3(24, 64), dim3(256), 0, stream>>>(emb, HH, W_ih, 2*HH, b_ih, (void*)giemb, (long long)H3, tgt);

  // ---- persistent recurrence ----
  {
    float* attn_out = out + OUT_ATT;
    float* out_ht   = out + OUT_HT;
    void* kargs[] = {
      (void*)&eh, (void*)&wcatbf, (void*)&bcat, (void*)&wihcbf, (void*)&giemb,
      (void*)&ukbf, (void*)&encbf, (void*)&Va, (void*)&bvp, (void*)&qbuf,
      (void*)&ghT, (void*)&ctxbf, (void*)&hsbf, (void*)&hsall,
      (void*)&attn_out, (void*)&out_ht
    };
    hipLaunchCooperativeKernel((void*)recurrence_coop, dim3(256), dim3(1024),
                               kargs, 0, stream);
  }

  // ---- output projection + log-softmax ----
  {
    long long n = (long long)VV*HH;     // W_out -> bf16 (aliases dead regions)
    cvt_f2b_kernel<<<dim3((unsigned)((n/4 + 255)/256)), dim3(256), 0, stream>>>(W_out, wbf, n);
  }
  gemm_out_mfma<<<dim3(250, 32), dim3(256), 0, stream>>>(hsall, wbf, b_out, out);
  logsoftmax_kernel<<<dim3(4096), dim3(256), 0, stream>>>(out);
}

// Round 5
// 3176.174 us; speedup vs baseline: 5.9624x; 2.7500x over previous
//
#include <hip/hip_runtime.h>
#include <math.h>

#define HH 512
#define VV 32000
#define BB 64
#define SS 64
#define TT 64
#define H3 1536

// ---- workspace layout (float offsets) ----
#define WS_GIEMB  0LL                       // 4096*1536 f32
#define WS_UKBF   6291456LL                 // 2M ushort
#define WS_ENCBF  7340032LL                 // 2M ushort
#define WS_WCATBF 8388608LL                 // 2048*512 ushort ([Wa;Whh] bf16)
#define WS_WIHCBF 8912896LL                 // 1536*512 ushort (W_ih ctx half)
#define WS_BCAT   9306112LL                 // 2048 f32 (ba; bhh)
#define WS_HBF    9308160LL                 // 2 x 64*512 ushort (h double-buffer bf16)
#define WS_H32    9340928LL                 // 2 x 64*512 f32   (h double-buffer fp32)
#define WS_HSALL  9406464LL                 // 4096*512 ushort (rows b*T+t)
// end ~10.46M floats (~42 MB). wbf (32000*512 us = 8.192M f) aliases
// ws[0 .. 8,192,000) = GIEMB+UKBF+ENCBF, all dead after the recurrence.

// output layout (floats)
#define OUT_HT  ((long long)BB*TT*VV)
#define OUT_ATT (OUT_HT + (long long)BB*HH)

typedef __attribute__((ext_vector_type(8))) short bf16x8;
typedef __attribute__((ext_vector_type(4))) float f32x4;

__device__ inline unsigned short f2b(float x) {
  unsigned u = __builtin_bit_cast(unsigned, x);
  unsigned r = (u + 0x7FFF + ((u >> 16) & 1)) >> 16;
  return (unsigned short)r;
}
__device__ inline float bc(unsigned u) { return __builtin_bit_cast(float, u); }
__device__ inline float frcp(float x) { return __builtin_amdgcn_rcpf(x); }
__device__ inline float tanh_fast(float x) { return 1.f - 2.f * frcp(__expf(2.f * x) + 1.f); }
__device__ inline float sigm(float x) { return frcp(1.f + __expf(-x)); }

__device__ inline float mac2(unsigned ha, unsigned wa, float acc) {
  acc = fmaf(bc(ha << 16), bc(wa << 16), acc);
  return fmaf(bc(ha & 0xffff0000u), bc(wa & 0xffff0000u), acc);
}

// ---------------------------------------------------------------------------
// fp32 NT GEMM (precompute). ROWMAP: 0 = A row m; 1 = emb gather. OUTBF: bf16 C.
// ---------------------------------------------------------------------------
template<int ROWMAP, int OUTBF>
__global__ __launch_bounds__(256) void gemm_nt(const float* __restrict__ A, int lda,
    const float* __restrict__ Bm, int ldb, const float* __restrict__ bias,
    void* __restrict__ Cv, long long ldc, const int* __restrict__ tok)
{
  __shared__ float As[16][68];
  __shared__ float Bs[16][68];
  const int tid = threadIdx.x;
  const int tx = tid & 15, ty = tid >> 4;
  const int lr = tid & 63, lc = (tid >> 6) << 2;
  const int m0 = blockIdx.y * 64, n0 = blockIdx.x * 64;

  long long arow;
  {
    int m = m0 + lr;
    if (ROWMAP == 0) {
      arow = (long long)m * lda;
    } else {
      int t = m >> 6, b = m & 63;
      int tk = (t == 0) ? 0 : tok[b * TT + t - 1];
      arow = (long long)tk * lda;
    }
  }
  const float* Ap = A + arow;
  const float* Bp = Bm + (long long)(n0 + lr) * ldb;

  float acc[4][4];
  #pragma unroll
  for (int i = 0; i < 4; i++)
    #pragma unroll
    for (int j = 0; j < 4; j++) acc[i][j] = 0.f;

  for (int k0 = 0; k0 < HH; k0 += 16) {
    float4 av = *(const float4*)(Ap + k0 + lc);
    float4 bv = *(const float4*)(Bp + k0 + lc);
    __syncthreads();
    As[lc+0][lr] = av.x; As[lc+1][lr] = av.y; As[lc+2][lr] = av.z; As[lc+3][lr] = av.w;
    Bs[lc+0][lr] = bv.x; Bs[lc+1][lr] = bv.y; Bs[lc+2][lr] = bv.z; Bs[lc+3][lr] = bv.w;
    __syncthreads();
    #pragma unroll
    for (int kk = 0; kk < 16; kk++) {
      float a[4], b[4];
      #pragma unroll
      for (int i = 0; i < 4; i++) a[i] = As[kk][i*16 + ty];
      #pragma unroll
      for (int j = 0; j < 4; j++) b[j] = Bs[kk][j*16 + tx];
      #pragma unroll
      for (int i = 0; i < 4; i++)
        #pragma unroll
        for (int j = 0; j < 4; j++) acc[i][j] += a[i] * b[j];
    }
  }

  #pragma unroll
  for (int j = 0; j < 4; j++) {
    int col = n0 + j*16 + tx;
    float bb = bias ? bias[col] : 0.f;
    #pragma unroll
    for (int i = 0; i < 4; i++) {
      int row = m0 + i*16 + ty;
      float v = acc[i][j] + bb;
      if (OUTBF) ((unsigned short*)Cv)[(long long)row * ldc + col] = f2b(v);
      else       ((float*)Cv)[(long long)row * ldc + col] = v;
    }
  }
}

// ---------------------------------------------------------------------------
// prep kernels
// ---------------------------------------------------------------------------
__global__ __launch_bounds__(256) void build_wcat_kernel(const float* __restrict__ Wa,
    const float* __restrict__ Whh, const float* __restrict__ ba,
    const float* __restrict__ bhh, unsigned short* __restrict__ wcatbf,
    float* __restrict__ bcat)
{
  long long i = (long long)blockIdx.x * 256 + threadIdx.x;   // 2048*512
  int j = (int)(i >> 9), k = (int)(i & 511);
  float v = (j < HH) ? Wa[(long long)j*HH + k] : Whh[(long long)(j - HH)*HH + k];
  wcatbf[i] = f2b(v);
  if (i < 2048) bcat[i] = (i < HH) ? ba[i] : bhh[i - HH];
}

__global__ __launch_bounds__(256) void build_wihc_kernel(const float* __restrict__ W_ih,
    unsigned short* __restrict__ wihcbf)
{
  long long i = (long long)blockIdx.x * 256 + threadIdx.x;   // 1536*512
  int j = (int)(i >> 9), k = (int)(i & 511);
  wihcbf[i] = f2b(W_ih[(long long)j*1024 + 512 + k]);
}

__global__ __launch_bounds__(256) void cvt_f2b_kernel(const float* __restrict__ in,
    unsigned short* __restrict__ outp, long long n)
{
  long long i = ((long long)blockIdx.x * 256 + threadIdx.x) * 4;
  if (i >= n) return;
  float4 v = *(const float4*)(in + i);
  ushort4 r = { f2b(v.x), f2b(v.y), f2b(v.z), f2b(v.w) };
  *(ushort4*)(outp + i) = r;
}

__global__ __launch_bounds__(256) void hinit_kernel(const float* __restrict__ eh,
    unsigned short* __restrict__ hbf0, float* __restrict__ h320)
{
  int i = blockIdx.x * 256 + threadIdx.x;   // 32768
  float v = eh[i];
  hbf0[i] = f2b(v);
  h320[i] = v;
}

// ---------------------------------------------------------------------------
// Fused decode step. Grid 256 = (b = bid>>2, qr = bid&3), 512 threads.
// Block does: full q (dup x4), scores+softmax+ctx (dup x4), then gh/gic/gates
// for its private 384-row j-slice {g*512 + qr*128 + [0,128)}.
// h double-buffered across launches (read t&1, write (t+1)&1).
// ---------------------------------------------------------------------------
__global__ __launch_bounds__(512, 2) void step_kernel(int t,
    const unsigned short* __restrict__ wcatbf,   // [2048][512]
    const unsigned short* __restrict__ wihcbf,   // [1536][512]
    const float* __restrict__ bcat,              // [2048]
    const float* __restrict__ giemb,             // [T*B][1536] (incl b_ih)
    const unsigned short* __restrict__ ukbf,     // [B*S][512]
    const unsigned short* __restrict__ encbf,    // [B*S][512]
    const float* __restrict__ Va, const float* __restrict__ bvp,
    const unsigned short* __restrict__ hbf_r,    // h_{t-1} bf16
    const float* __restrict__ h32_r,             // h_{t-1} fp32
    unsigned short* __restrict__ hbf_w, float* __restrict__ h32_w,
    unsigned short* __restrict__ hsall,          // [B*T][512]
    float* __restrict__ attn_out, float* __restrict__ out_ht)
{
  const int bid = blockIdx.x;
  const int b = bid >> 2, qr = bid & 3;
  const int tid = threadIdx.x;
  const int sub = tid & 15;          // k-slice owner (32 elems)
  const int jg  = tid >> 4;          // j-group 0..31

  __shared__ float qsp[16][40];      // q, row sub holds k in [sub*32, sub*32+32)
  __shared__ float ctp[16][40];      // ctx, same layout
  __shared__ float sc[SS], sw[SS];
  __shared__ float ghv[384], gicv[384];

  // h slice (bf16 packed) and Va slice -> registers
  unsigned hreg[16];
  {
    const uint4* hp = (const uint4*)(hbf_r + b*512 + sub*32);
    #pragma unroll
    for (int i = 0; i < 4; ++i) {
      uint4 v = hp[i];
      hreg[i*4+0] = v.x; hreg[i*4+1] = v.y; hreg[i*4+2] = v.z; hreg[i*4+3] = v.w;
    }
  }
  float vreg[32];
  {
    const float4* vp = (const float4*)(Va + sub*32);
    #pragma unroll
    for (int i = 0; i < 8; ++i) {
      float4 v = vp[i];
      vreg[i*4+0] = v.x; vreg[i*4+1] = v.y; vreg[i*4+2] = v.z; vreg[i*4+3] = v.w;
    }
  }

  // ---- q = h @ Wa^T + ba (full 512 cols) ----
  #pragma unroll 2
  for (int p = 0; p < 16; ++p) {
    int j = p*32 + jg;
    const uint4* wp = (const uint4*)(wcatbf + (long long)j*512 + sub*32);
    float acc = 0.f;
    #pragma unroll
    for (int i = 0; i < 4; ++i) {
      uint4 wv = wp[i];
      acc = mac2(hreg[i*4+0], wv.x, acc);
      acc = mac2(hreg[i*4+1], wv.y, acc);
      acc = mac2(hreg[i*4+2], wv.z, acc);
      acc = mac2(hreg[i*4+3], wv.w, acc);
    }
    acc += __shfl_xor(acc, 1);
    acc += __shfl_xor(acc, 2);
    acc += __shfl_xor(acc, 4);
    acc += __shfl_xor(acc, 8);
    if (sub == 0) qsp[p][jg] = acc + bcat[j];
  }
  __syncthreads();

  // ---- q slice -> registers ----
  float qreg[32];
  {
    const float4* qp = (const float4*)&qsp[sub][0];
    #pragma unroll
    for (int i = 0; i < 8; ++i) {
      float4 v = qp[i];
      qreg[i*4+0] = v.x; qreg[i*4+1] = v.y; qreg[i*4+2] = v.z; qreg[i*4+3] = v.w;
    }
  }

  // ---- scores ----
  const float bv0 = bvp[0];
  #pragma unroll
  for (int it = 0; it < 2; ++it) {
    int s = it*32 + jg;
    const uint4* up = (const uint4*)(ukbf + (long long)(b*SS + s)*512 + sub*32);
    float p_ = 0.f;
    #pragma unroll
    for (int i = 0; i < 4; ++i) {
      uint4 uv = up[i];
      int e = i*8;
      p_ = fmaf(vreg[e+0], tanh_fast(qreg[e+0] + bc(uv.x << 16)), p_);
      p_ = fmaf(vreg[e+1], tanh_fast(qreg[e+1] + bc(uv.x & 0xffff0000u)), p_);
      p_ = fmaf(vreg[e+2], tanh_fast(qreg[e+2] + bc(uv.y << 16)), p_);
      p_ = fmaf(vreg[e+3], tanh_fast(qreg[e+3] + bc(uv.y & 0xffff0000u)), p_);
      p_ = fmaf(vreg[e+4], tanh_fast(qreg[e+4] + bc(uv.z << 16)), p_);
      p_ = fmaf(vreg[e+5], tanh_fast(qreg[e+5] + bc(uv.z & 0xffff0000u)), p_);
      p_ = fmaf(vreg[e+6], tanh_fast(qreg[e+6] + bc(uv.w << 16)), p_);
      p_ = fmaf(vreg[e+7], tanh_fast(qreg[e+7] + bc(uv.w & 0xffff0000u)), p_);
    }
    p_ += __shfl_xor(p_, 1);
    p_ += __shfl_xor(p_, 2);
    p_ += __shfl_xor(p_, 4);
    p_ += __shfl_xor(p_, 8);
    if (sub == 0) sc[s] = p_ + bv0;
  }
  __syncthreads();

  // ---- softmax over S=64 (wave 0) ----
  if (tid < 64) {
    float x = sc[tid], mx = x;
    #pragma unroll
    for (int off = 32; off; off >>= 1) mx = fmaxf(mx, __shfl_xor(mx, off));
    float e = __expf(x - mx), sm = e;
    #pragma unroll
    for (int off = 32; off; off >>= 1) sm += __shfl_xor(sm, off);
    float w_ = e * frcp(sm);
    sw[tid] = w_;
    if (qr == 0) attn_out[((long long)b*TT + t)*SS + tid] = w_;
  }
  __syncthreads();

  // ---- ctx[k] = sum_s sw[s] * enc[b][s][k] ----
  {
    float a = 0.f;
    const unsigned short* ep = encbf + (long long)b*SS*512 + tid;
    #pragma unroll 8
    for (int s = 0; s < SS; ++s)
      a = fmaf(sw[s], bc(((unsigned)ep[s*512]) << 16), a);
    ctp[tid >> 5][tid & 31] = a;
  }
  __syncthreads();

  // ---- ctx slice -> registers ----
  float ctxreg[32];
  {
    const float4* cp = (const float4*)&ctp[sub][0];
    #pragma unroll
    for (int i = 0; i < 8; ++i) {
      float4 v = cp[i];
      ctxreg[i*4+0] = v.x; ctxreg[i*4+1] = v.y; ctxreg[i*4+2] = v.z; ctxreg[i*4+3] = v.w;
    }
  }

  // ---- gh & gic for 384-row slice ----
  #pragma unroll 2
  for (int p = 0; p < 12; ++p) {
    int r = p*32 + jg;                    // 0..383
    int g = r >> 7, jj = r & 127;
    long long j = (long long)g*512 + qr*128 + jj;
    const uint4* hw = (const uint4*)(wcatbf + (512LL + j)*512 + sub*32);
    const uint4* cw = (const uint4*)(wihcbf + j*512 + sub*32);
    float ga = 0.f, ca = 0.f;
    #pragma unroll
    for (int i = 0; i < 4; ++i) {
      uint4 wv = hw[i];
      uint4 cv = cw[i];
      int e = i*8;
      ga = mac2(hreg[i*4+0], wv.x, ga);
      ga = mac2(hreg[i*4+1], wv.y, ga);
      ga = mac2(hreg[i*4+2], wv.z, ga);
      ga = mac2(hreg[i*4+3], wv.w, ga);
      ca = fmaf(ctxreg[e+0], bc(cv.x << 16), ca);
      ca = fmaf(ctxreg[e+1], bc(cv.x & 0xffff0000u), ca);
      ca = fmaf(ctxreg[e+2], bc(cv.y << 16), ca);
      ca = fmaf(ctxreg[e+3], bc(cv.y & 0xffff0000u), ca);
      ca = fmaf(ctxreg[e+4], bc(cv.z << 16), ca);
      ca = fmaf(ctxreg[e+5], bc(cv.z & 0xffff0000u), ca);
      ca = fmaf(ctxreg[e+6], bc(cv.w << 16), ca);
      ca = fmaf(ctxreg[e+7], bc(cv.w & 0xffff0000u), ca);
    }
    ga += __shfl_xor(ga, 1); ca += __shfl_xor(ca, 1);
    ga += __shfl_xor(ga, 2); ca += __shfl_xor(ca, 2);
    ga += __shfl_xor(ga, 4); ca += __shfl_xor(ca, 4);
    ga += __shfl_xor(ga, 8); ca += __shfl_xor(ca, 8);
    if (sub == 0) { ghv[r] = ga + bcat[512 + j]; gicv[r] = ca; }
  }
  __syncthreads();

  // ---- gates + h update (128 cols) ----
  if (tid < 128) {
    const int jj = tid, col = qr*128 + jj;
    const long long gb = ((long long)t*BB + b)*H3 + qr*128 + jj;
    float gir = giemb[gb], giz = giemb[gb + 512], gin = giemb[gb + 1024];
    float r = sigm(gir + gicv[jj]       + ghv[jj]);
    float z = sigm(giz + gicv[128 + jj] + ghv[128 + jj]);
    float n = tanh_fast(gin + gicv[256 + jj] + r * ghv[256 + jj]);
    float hold = h32_r[b*512 + col];
    float hn = (1.f - z) * n + z * hold;
    h32_w[b*512 + col] = hn;
    unsigned short hb = f2b(hn);
    hbf_w[b*512 + col] = hb;
    hsall[((long long)b*TT + t)*512 + col] = hb;
    if (t == TT - 1) out_ht[b*512 + col] = hn;
  }
}

// ---------------------------------------------------------------------------
// Output projection: bf16 MFMA 16x16x32, 128x128 tile, BK=32, 4 waves.
// ---------------------------------------------------------------------------
__global__ __launch_bounds__(256) void gemm_out_mfma(const unsigned short* __restrict__ A,
    const unsigned short* __restrict__ Bw, const float* __restrict__ bias,
    float* __restrict__ C)
{
  __shared__ unsigned short As[128*32];
  __shared__ unsigned short Bs[128*32];
  const int tid = threadIdx.x;
  const int w = tid >> 6, l = tid & 63;
  const int m0 = blockIdx.y * 128, n0 = blockIdx.x * 128;
  const int wr = w >> 1, wc = w & 1;

  f32x4 acc[4][4];
  #pragma unroll
  for (int i = 0; i < 4; i++)
    #pragma unroll
    for (int j = 0; j < 4; j++) acc[i][j] = (f32x4){0.f, 0.f, 0.f, 0.f};

  const int srow = l >> 2;
  const int scol = (l & 3) * 8;

  for (int k0 = 0; k0 < HH; k0 += 32) {
    __syncthreads();
    #pragma unroll
    for (int q = 0; q < 2; ++q) {
      int r = w*32 + q*16 + srow;
      __builtin_amdgcn_global_load_lds(
          (const __attribute__((address_space(1))) void*)(A + (long long)(m0 + r)*HH + k0 + scol),
          (__attribute__((address_space(3))) void*)(As + r*32 + scol), 16, 0, 0);
      __builtin_amdgcn_global_load_lds(
          (const __attribute__((address_space(1))) void*)(Bw + (long long)(n0 + r)*HH + k0 + scol),
          (__attribute__((address_space(3))) void*)(Bs + r*32 + scol), 16, 0, 0);
    }
    __syncthreads();

    bf16x8 a[4], b[4];
    #pragma unroll
    for (int mi = 0; mi < 4; mi++)
      a[mi] = *(const bf16x8*)&As[(wr*64 + mi*16 + (l & 15))*32 + (l >> 4)*8];
    #pragma unroll
    for (int ni = 0; ni < 4; ni++)
      b[ni] = *(const bf16x8*)&Bs[(wc*64 + ni*16 + (l & 15))*32 + (l >> 4)*8];
    #pragma unroll
    for (int mi = 0; mi < 4; mi++)
      #pragma unroll
      for (int ni = 0; ni < 4; ni++)
        acc[mi][ni] = __builtin_amdgcn_mfma_f32_16x16x32_bf16(a[mi], b[ni], acc[mi][ni], 0, 0, 0);
  }

  #pragma unroll
  for (int mi = 0; mi < 4; mi++) {
    #pragma unroll
    for (int ni = 0; ni < 4; ni++) {
      int col = n0 + wc*64 + ni*16 + (l & 15);
      float bb = bias[col];
      #pragma unroll
      for (int r2 = 0; r2 < 4; r2++) {
        int row = m0 + wr*64 + mi*16 + (l >> 4)*4 + r2;
        C[(long long)row*VV + col] = acc[mi][ni][r2] + bb;
      }
    }
  }
}

// ---------------------------------------------------------------------------
// In-place log-softmax over rows of V=32000
// ---------------------------------------------------------------------------
__global__ __launch_bounds__(256) void logsoftmax_kernel(float* __restrict__ lp)
{
  float* p = lp + (long long)blockIdx.x * VV;
  const int tid = threadIdx.x;
  float m = -1e30f, s = 0.f;
  for (int v = tid; v < VV; v += 256) {
    float x = p[v];
    if (x > m) { s = s * __expf(m - x) + 1.f; m = x; }
    else       { s += __expf(x - m); }
  }
  __shared__ float rm[256], rs[256];
  rm[tid] = m; rs[tid] = s;
  __syncthreads();
  for (int off = 128; off; off >>= 1) {
    if (tid < off) {
      float m2 = rm[tid + off], s2 = rs[tid + off];
      float mm = fmaxf(rm[tid], m2);
      rs[tid] = rs[tid] * __expf(rm[tid] - mm) + s2 * __expf(m2 - mm);
      rm[tid] = mm;
    }
    __syncthreads();
  }
  const float L = rm[0] + logf(rs[0]);
  for (int v = tid; v < VV; v += 256) p[v] -= L;
}

// ---------------------------------------------------------------------------
extern "C" void kernel_launch(void* const* d_in, const int* in_sizes, int n_in,
                              void* d_out, int out_size, void* d_ws, size_t ws_size,
                              hipStream_t stream)
{
  const float* enc   = (const float*)d_in[0];
  const float* eh    = (const float*)d_in[1];
  const int*   tgt   = (const int*)  d_in[2];
  const float* emb   = (const float*)d_in[3];
  const float* Wa    = (const float*)d_in[4];
  const float* ba    = (const float*)d_in[5];
  const float* Ua    = (const float*)d_in[6];
  const float* bu    = (const float*)d_in[7];
  const float* Va    = (const float*)d_in[8];
  const float* bvp   = (const float*)d_in[9];
  const float* W_ih  = (const float*)d_in[10];
  const float* W_hh  = (const float*)d_in[11];
  const float* b_ih  = (const float*)d_in[12];
  const float* b_hh  = (const float*)d_in[13];
  const float* W_out = (const float*)d_in[14];
  const float* b_out = (const float*)d_in[15];

  float* out = (float*)d_out;
  float* ws  = (float*)d_ws;

  float* giemb = ws + WS_GIEMB;
  unsigned short* ukbf   = (unsigned short*)(ws + WS_UKBF);
  unsigned short* encbf  = (unsigned short*)(ws + WS_ENCBF);
  unsigned short* wcatbf = (unsigned short*)(ws + WS_WCATBF);
  unsigned short* wihcbf = (unsigned short*)(ws + WS_WIHCBF);
  float* bcat = ws + WS_BCAT;
  unsigned short* hbf0 = (unsigned short*)(ws + WS_HBF);
  unsigned short* hbf1 = hbf0 + BB*HH;
  float* h320 = ws + WS_H32;
  float* h321 = h320 + BB*HH;
  unsigned short* hsall = (unsigned short*)(ws + WS_HSALL);
  unsigned short* wbf   = (unsigned short*)ws;   // aliases giemb+ukbf+encbf post-recurrence

  float* attn_out = out + OUT_ATT;
  float* out_ht   = out + OUT_HT;

  // ---- prep ----
  build_wcat_kernel<<<dim3(4096), dim3(256), 0, stream>>>(Wa, W_hh, ba, b_hh, wcatbf, bcat);
  build_wihc_kernel<<<dim3(3072), dim3(256), 0, stream>>>(W_ih, wihcbf);
  {
    long long n = (long long)BB*SS*HH;
    cvt_f2b_kernel<<<dim3((unsigned)(n/4/256)), dim3(256), 0, stream>>>(enc, encbf, n);
  }
  hinit_kernel<<<dim3(128), dim3(256), 0, stream>>>(eh, hbf0, h320);
  gemm_nt<0,1><<<dim3(8, 64), dim3(256), 0, stream>>>(enc, HH, Ua, HH, bu, (void*)ukbf, (long long)HH, nullptr);
  gemm_nt<1,0><<<dim3(24, 64), dim3(256), 0, stream>>>(emb, HH, W_ih, 2*HH, b_ih, (void*)giemb, (long long)H3, tgt);

  // ---- recurrence: 64 fused-step launches ----
  for (int t = 0; t < TT; ++t) {
    const unsigned short* hr = (t & 1) ? hbf1 : hbf0;
    const float*          h32r = (t & 1) ? h321 : h320;
    unsigned short*       hw = (t & 1) ? hbf0 : hbf1;
    float*                h32w = (t & 1) ? h320 : h321;
    step_kernel<<<dim3(256), dim3(512), 0, stream>>>(t, wcatbf, wihcbf, bcat,
        giemb, ukbf, encbf, Va, bvp, hr, h32r, hw, h32w, hsall, attn_out, out_ht);
  }

  // ---- output projection + log-softmax ----
  {
    long long n = (long long)VV*HH;
    cvt_f2b_kernel<<<dim3((unsigned)(n/4/256)), dim3(256), 0, stream>>>(W_out, wbf, n);
  }
  gemm_out_mfma<<<dim3(250, 32), dim3(256), 0, stream>>>(hsall, wbf, b_out, out);
  logsoftmax_kernel<<<dim3(4096), dim3(256), 0, stream>>>(out);
}

// Round 6
// 2917.740 us; speedup vs baseline: 6.4905x; 1.0886x over previous
//
#include <hip/hip_runtime.h>
#include <math.h>

#define HH 512
#define VV 32000
#define BB 64
#define SS 64
#define TT 64
#define H3 1536

// ---- workspace layout (float offsets) ----
#define WS_GIEMB  0LL                       // 4096*1536 f32
#define WS_UKBF   6291456LL                 // 2M ushort
#define WS_ENCBF  7340032LL                 // 2M ushort
#define WS_WCATBF 8388608LL                 // 2048*512 ushort ([Wa;Whh] bf16)
#define WS_WIHCBF 8912896LL                 // 1536*512 ushort (W_ih ctx half)
#define WS_BCAT   9306112LL                 // 2048 f32 (ba; bhh)
#define WS_HBF    9308160LL                 // 2 x 64*512 ushort (h double-buffer bf16)
#define WS_H32    9340928LL                 // 2 x 64*512 f32   (h double-buffer fp32)
#define WS_CTXBF  9406464LL                 // 64*512 ushort (ctx bf16)
#define WS_HSALL  9422848LL                 // 4096*512 ushort (rows b*T+t)
// end ~10.47M floats (~42 MB). wbf (32000*512 us = 8.192M f) aliases
// ws[0 .. 8,192,000) = GIEMB+UKBF+ENCBF, all dead after the recurrence.

// output layout (floats)
#define OUT_HT  ((long long)BB*TT*VV)
#define OUT_ATT (OUT_HT + (long long)BB*HH)

typedef __attribute__((ext_vector_type(8))) short bf16x8;
typedef __attribute__((ext_vector_type(4))) float f32x4;

__device__ inline unsigned short f2b(float x) {
  unsigned u = __builtin_bit_cast(unsigned, x);
  unsigned r = (u + 0x7FFF + ((u >> 16) & 1)) >> 16;
  return (unsigned short)r;
}
__device__ inline float bc(unsigned u) { return __builtin_bit_cast(float, u); }
__device__ inline float frcp(float x) { return __builtin_amdgcn_rcpf(x); }
__device__ inline float tanh_fast(float x) { return 1.f - 2.f * frcp(__expf(2.f * x) + 1.f); }
__device__ inline float sigm(float x) { return frcp(1.f + __expf(-x)); }

__device__ inline float mac2(unsigned ha, unsigned wa, float acc) {
  acc = fmaf(bc(ha << 16), bc(wa << 16), acc);
  return fmaf(bc(ha & 0xffff0000u), bc(wa & 0xffff0000u), acc);
}

// ---------------------------------------------------------------------------
// fp32 NT GEMM (precompute). ROWMAP: 0 = A row m; 1 = emb gather. OUTBF: bf16 C.
// ---------------------------------------------------------------------------
template<int ROWMAP, int OUTBF>
__global__ __launch_bounds__(256) void gemm_nt(const float* __restrict__ A, int lda,
    const float* __restrict__ Bm, int ldb, const float* __restrict__ bias,
    void* __restrict__ Cv, long long ldc, const int* __restrict__ tok)
{
  __shared__ float As[16][68];
  __shared__ float Bs[16][68];
  const int tid = threadIdx.x;
  const int tx = tid & 15, ty = tid >> 4;
  const int lr = tid & 63, lc = (tid >> 6) << 2;
  const int m0 = blockIdx.y * 64, n0 = blockIdx.x * 64;

  long long arow;
  {
    int m = m0 + lr;
    if (ROWMAP == 0) {
      arow = (long long)m * lda;
    } else {
      int t = m >> 6, b = m & 63;
      int tk = (t == 0) ? 0 : tok[b * TT + t - 1];
      arow = (long long)tk * lda;
    }
  }
  const float* Ap = A + arow;
  const float* Bp = Bm + (long long)(n0 + lr) * ldb;

  float acc[4][4];
  #pragma unroll
  for (int i = 0; i < 4; i++)
    #pragma unroll
    for (int j = 0; j < 4; j++) acc[i][j] = 0.f;

  for (int k0 = 0; k0 < HH; k0 += 16) {
    float4 av = *(const float4*)(Ap + k0 + lc);
    float4 bv = *(const float4*)(Bp + k0 + lc);
    __syncthreads();
    As[lc+0][lr] = av.x; As[lc+1][lr] = av.y; As[lc+2][lr] = av.z; As[lc+3][lr] = av.w;
    Bs[lc+0][lr] = bv.x; Bs[lc+1][lr] = bv.y; Bs[lc+2][lr] = bv.z; Bs[lc+3][lr] = bv.w;
    __syncthreads();
    #pragma unroll
    for (int kk = 0; kk < 16; kk++) {
      float a[4], b[4];
      #pragma unroll
      for (int i = 0; i < 4; i++) a[i] = As[kk][i*16 + ty];
      #pragma unroll
      for (int j = 0; j < 4; j++) b[j] = Bs[kk][j*16 + tx];
      #pragma unroll
      for (int i = 0; i < 4; i++)
        #pragma unroll
        for (int j = 0; j < 4; j++) acc[i][j] += a[i] * b[j];
    }
  }

  #pragma unroll
  for (int j = 0; j < 4; j++) {
    int col = n0 + j*16 + tx;
    float bb = bias ? bias[col] : 0.f;
    #pragma unroll
    for (int i = 0; i < 4; i++) {
      int row = m0 + i*16 + ty;
      float v = acc[i][j] + bb;
      if (OUTBF) ((unsigned short*)Cv)[(long long)row * ldc + col] = f2b(v);
      else       ((float*)Cv)[(long long)row * ldc + col] = v;
    }
  }
}

// ---------------------------------------------------------------------------
// prep kernels
// ---------------------------------------------------------------------------
__global__ __launch_bounds__(256) void build_wcat_kernel(const float* __restrict__ Wa,
    const float* __restrict__ Whh, const float* __restrict__ ba,
    const float* __restrict__ bhh, unsigned short* __restrict__ wcatbf,
    float* __restrict__ bcat)
{
  long long i = (long long)blockIdx.x * 256 + threadIdx.x;   // 2048*512
  int j = (int)(i >> 9), k = (int)(i & 511);
  float v = (j < HH) ? Wa[(long long)j*HH + k] : Whh[(long long)(j - HH)*HH + k];
  wcatbf[i] = f2b(v);
  if (i < 2048) bcat[i] = (i < HH) ? ba[i] : bhh[i - HH];
}

__global__ __launch_bounds__(256) void build_wihc_kernel(const float* __restrict__ W_ih,
    unsigned short* __restrict__ wihcbf)
{
  long long i = (long long)blockIdx.x * 256 + threadIdx.x;   // 1536*512
  int j = (int)(i >> 9), k = (int)(i & 511);
  wihcbf[i] = f2b(W_ih[(long long)j*1024 + 512 + k]);
}

__global__ __launch_bounds__(256) void cvt_f2b_kernel(const float* __restrict__ in,
    unsigned short* __restrict__ outp, long long n)
{
  long long i = ((long long)blockIdx.x * 256 + threadIdx.x) * 4;
  if (i >= n) return;
  float4 v = *(const float4*)(in + i);
  ushort4 r = { f2b(v.x), f2b(v.y), f2b(v.z), f2b(v.w) };
  *(ushort4*)(outp + i) = r;
}

__global__ __launch_bounds__(256) void hinit_kernel(const float* __restrict__ eh,
    unsigned short* __restrict__ hbf0, float* __restrict__ h320)
{
  int i = blockIdx.x * 256 + threadIdx.x;   // 32768
  float v = eh[i];
  hbf0[i] = f2b(v);
  h320[i] = v;
}

// ---------------------------------------------------------------------------
// stepA: per-batch q + attention. Grid 64 (b), 512 threads.
// q[j] = h_{t-1}[b]·Wa[j] + ba[j]; scores; softmax; ctx -> ctxbf (bf16).
// Zero weight duplication across blocks owning different b? (Wa is shared:
// 8 blocks/XCD stream it from L2 - 4MB/XCD/step.)
// ---------------------------------------------------------------------------
__global__ __launch_bounds__(512) void stepA_kernel(int t,
    const unsigned short* __restrict__ wcatbf, const float* __restrict__ bcat,
    const unsigned short* __restrict__ ukbf, const unsigned short* __restrict__ encbf,
    const float* __restrict__ Va, const float* __restrict__ bvp,
    const unsigned short* __restrict__ hbf_r,
    unsigned short* __restrict__ ctxbf, float* __restrict__ attn_out)
{
  const int b = blockIdx.x, tid = threadIdx.x;
  __shared__ unsigned hsh[256];          // h[b] bf16 pairs
  __shared__ float qs2[8][68];           // q padded: [k>>6][k&63]
  __shared__ float vsh[8][68];           // Va padded same layout
  __shared__ float sc[SS], sw[SS];

  if (tid < 256) hsh[tid] = ((const unsigned*)(hbf_r + (long long)b*512))[tid];
  vsh[tid >> 6][tid & 63] = Va[tid];
  __syncthreads();

  // ---- q: one column per thread ----
  {
    const int j = tid;
    const uint4* wp = (const uint4*)(wcatbf + (long long)j*512);
    float acc = 0.f;
    #pragma unroll 8
    for (int i = 0; i < 64; ++i) {
      uint4 wv = wp[i];
      acc = mac2(hsh[i*4+0], wv.x, acc);
      acc = mac2(hsh[i*4+1], wv.y, acc);
      acc = mac2(hsh[i*4+2], wv.z, acc);
      acc = mac2(hsh[i*4+3], wv.w, acc);
    }
    qs2[j >> 6][j & 63] = acc + bcat[j];
  }
  __syncthreads();

  // ---- scores: (s = tid>>3, sub = tid&7), 64 k each ----
  {
    const int s = tid >> 3, sub = tid & 7;
    const uint4* up = (const uint4*)(ukbf + ((long long)(b*SS + s))*512 + sub*64);
    const float* qp = &qs2[sub][0];
    const float* vp = &vsh[sub][0];
    float p_ = 0.f;
    #pragma unroll
    for (int i = 0; i < 8; ++i) {
      uint4 uv = up[i];
      int e = i*8;
      p_ = fmaf(vp[e+0], tanh_fast(qp[e+0] + bc(uv.x << 16)), p_);
      p_ = fmaf(vp[e+1], tanh_fast(qp[e+1] + bc(uv.x & 0xffff0000u)), p_);
      p_ = fmaf(vp[e+2], tanh_fast(qp[e+2] + bc(uv.y << 16)), p_);
      p_ = fmaf(vp[e+3], tanh_fast(qp[e+3] + bc(uv.y & 0xffff0000u)), p_);
      p_ = fmaf(vp[e+4], tanh_fast(qp[e+4] + bc(uv.z << 16)), p_);
      p_ = fmaf(vp[e+5], tanh_fast(qp[e+5] + bc(uv.z & 0xffff0000u)), p_);
      p_ = fmaf(vp[e+6], tanh_fast(qp[e+6] + bc(uv.w << 16)), p_);
      p_ = fmaf(vp[e+7], tanh_fast(qp[e+7] + bc(uv.w & 0xffff0000u)), p_);
    }
    p_ += __shfl_xor(p_, 1);
    p_ += __shfl_xor(p_, 2);
    p_ += __shfl_xor(p_, 4);
    if (sub == 0) sc[s] = p_ + bvp[0];
  }
  __syncthreads();

  // ---- softmax (wave 0) ----
  if (tid < 64) {
    float x = sc[tid], mx = x;
    #pragma unroll
    for (int off = 32; off; off >>= 1) mx = fmaxf(mx, __shfl_xor(mx, off));
    float e = __expf(x - mx), sm = e;
    #pragma unroll
    for (int off = 32; off; off >>= 1) sm += __shfl_xor(sm, off);
    float w_ = e * frcp(sm);
    sw[tid] = w_;
    attn_out[((long long)b*TT + t)*SS + tid] = w_;
  }
  __syncthreads();

  // ---- ctx[k] = sum_s sw[s] * enc[b][s][k] ----
  {
    float a = 0.f;
    const unsigned short* ep = encbf + (long long)b*SS*512 + tid;
    #pragma unroll 8
    for (int s = 0; s < SS; ++s)
      a = fmaf(sw[s], bc(((unsigned)ep[s*512]) << 16), a);
    ctxbf[b*512 + tid] = f2b(a);
  }
}

// ---------------------------------------------------------------------------
// stepB: gh + gic + gates. Grid 256 (j-slice of 2), 768 threads.
// Thread = (b = tid/12, d = tid%12): one full 512-dot.
//   d 0..5:  gh  (src h,   row = 512 + g*512 + j0+jj in wcatbf)
//   d 6..11: gic (src ctx, row = g*512 + j0+jj in wihcbf)
// Epilogue (128 threads): gates -> h_t.
// ---------------------------------------------------------------------------
__global__ __launch_bounds__(768) void stepB_kernel(int t,
    const unsigned short* __restrict__ wcatbf, const unsigned short* __restrict__ wihcbf,
    const float* __restrict__ bcat, const float* __restrict__ giemb,
    const unsigned short* __restrict__ hbf_r, const float* __restrict__ h32_r,
    const unsigned short* __restrict__ ctxbf,
    unsigned short* __restrict__ hbf_w, float* __restrict__ h32_w,
    unsigned short* __restrict__ hsall, float* __restrict__ out_ht)
{
  const int a = blockIdx.x, tid = threadIdx.x;
  const int j0 = a * 2;
  __shared__ unsigned wsh[12*260];       // 12 weight rows, 260-uint padded
  __shared__ float dsh[64*13];           // dot results [b][d] padded

  // stage 12 weight rows
  for (int i = tid; i < 12*256; i += 768) {
    int rw = i >> 8, c = i & 255;
    int jj = rw & 1;
    int half = (rw >= 6);
    int g = (half ? (rw - 6) : rw) >> 1;
    const unsigned short* base = half
        ? (wihcbf + ((long long)(g*512 + j0 + jj))*512)
        : (wcatbf + ((long long)(512 + g*512 + j0 + jj))*512);
    wsh[rw*260 + c] = ((const unsigned*)base)[c];
  }
  __syncthreads();

  // one dot per thread
  {
    const int b = tid / 12, d = tid - b*12;
    const unsigned* wrow = wsh + d*260;
    const unsigned short* srow = (d < 6) ? (hbf_r + (long long)b*512)
                                         : (ctxbf + (long long)b*512);
    float acc = 0.f;
    #pragma unroll 8
    for (int i = 0; i < 64; ++i) {
      uint4 wv = *(const uint4*)(wrow + i*4);
      uint4 sv = *(const uint4*)(srow + i*8);
      acc = mac2(sv.x, wv.x, acc);
      acc = mac2(sv.y, wv.y, acc);
      acc = mac2(sv.z, wv.z, acc);
      acc = mac2(sv.w, wv.w, acc);
    }
    dsh[b*13 + d] = acc;
  }
  __syncthreads();

  // gates epilogue: 128 threads = (b = tid>>1, jj = tid&1)
  if (tid < 128) {
    const int b = tid >> 1, jj = tid & 1;
    const int j = j0 + jj;
    const long long gb = ((long long)t*BB + b)*H3 + j;
    float gir = giemb[gb], giz = giemb[gb + 512], gin = giemb[gb + 1024];
    float ghr = dsh[b*13 + 0 + jj] + bcat[512 + j];
    float ghz = dsh[b*13 + 2 + jj] + bcat[1024 + j];
    float ghn = dsh[b*13 + 4 + jj] + bcat[1536 + j];
    float gcr = dsh[b*13 + 6 + jj];
    float gcz = dsh[b*13 + 8 + jj];
    float gcn = dsh[b*13 + 10 + jj];
    float r = sigm(gir + gcr + ghr);
    float z = sigm(giz + gcz + ghz);
    float n = tanh_fast(gin + gcn + r * ghn);
    float hold = h32_r[b*512 + j];
    float hn = (1.f - z) * n + z * hold;
    h32_w[b*512 + j] = hn;
    unsigned short hb = f2b(hn);
    hbf_w[b*512 + j] = hb;
    hsall[((long long)b*TT + t)*512 + j] = hb;
    if (t == TT - 1) out_ht[b*512 + j] = hn;
  }
}

// ---------------------------------------------------------------------------
// Output projection: bf16 MFMA 16x16x32, 128x128 tile, BK=32, 4 waves.
// ---------------------------------------------------------------------------
__global__ __launch_bounds__(256) void gemm_out_mfma(const unsigned short* __restrict__ A,
    const unsigned short* __restrict__ Bw, const float* __restrict__ bias,
    float* __restrict__ C)
{
  __shared__ unsigned short As[128*32];
  __shared__ unsigned short Bs[128*32];
  const int tid = threadIdx.x;
  const int w = tid >> 6, l = tid & 63;
  const int m0 = blockIdx.y * 128, n0 = blockIdx.x * 128;
  const int wr = w >> 1, wc = w & 1;

  f32x4 acc[4][4];
  #pragma unroll
  for (int i = 0; i < 4; i++)
    #pragma unroll
    for (int j = 0; j < 4; j++) acc[i][j] = (f32x4){0.f, 0.f, 0.f, 0.f};

  const int srow = l >> 2;
  const int scol = (l & 3) * 8;

  for (int k0 = 0; k0 < HH; k0 += 32) {
    __syncthreads();
    #pragma unroll
    for (int q = 0; q < 2; ++q) {
      int r = w*32 + q*16 + srow;
      __builtin_amdgcn_global_load_lds(
          (const __attribute__((address_space(1))) void*)(A + (long long)(m0 + r)*HH + k0 + scol),
          (__attribute__((address_space(3))) void*)(As + r*32 + scol), 16, 0, 0);
      __builtin_amdgcn_global_load_lds(
          (const __attribute__((address_space(1))) void*)(Bw + (long long)(n0 + r)*HH + k0 + scol),
          (__attribute__((address_space(3))) void*)(Bs + r*32 + scol), 16, 0, 0);
    }
    __syncthreads();

    bf16x8 a[4], b[4];
    #pragma unroll
    for (int mi = 0; mi < 4; mi++)
      a[mi] = *(const bf16x8*)&As[(wr*64 + mi*16 + (l & 15))*32 + (l >> 4)*8];
    #pragma unroll
    for (int ni = 0; ni < 4; ni++)
      b[ni] = *(const bf16x8*)&Bs[(wc*64 + ni*16 + (l & 15))*32 + (l >> 4)*8];
    #pragma unroll
    for (int mi = 0; mi < 4; mi++)
      #pragma unroll
      for (int ni = 0; ni < 4; ni++)
        acc[mi][ni] = __builtin_amdgcn_mfma_f32_16x16x32_bf16(a[mi], b[ni], acc[mi][ni], 0, 0, 0);
  }

  #pragma unroll
  for (int mi = 0; mi < 4; mi++) {
    #pragma unroll
    for (int ni = 0; ni < 4; ni++) {
      int col = n0 + wc*64 + ni*16 + (l & 15);
      float bb = bias[col];
      #pragma unroll
      for (int r2 = 0; r2 < 4; r2++) {
        int row = m0 + wr*64 + mi*16 + (l >> 4)*4 + r2;
        C[(long long)row*VV + col] = acc[mi][ni][r2] + bb;
      }
    }
  }
}

// ---------------------------------------------------------------------------
// In-place log-softmax over rows of V=32000, float4-vectorized (8000 f4/row)
// ---------------------------------------------------------------------------
__global__ __launch_bounds__(512) void logsoftmax_kernel(float* __restrict__ lp)
{
  float4* p4 = (float4*)(lp + (long long)blockIdx.x * VV);
  const int tid = threadIdx.x;
  float m = -1e30f, s = 0.f;
  for (int v = tid; v < 8000; v += 512) {
    float4 x = p4[v];
    float mx = fmaxf(fmaxf(x.x, x.y), fmaxf(x.z, x.w));
    float e = __expf(x.x - mx) + __expf(x.y - mx) + __expf(x.z - mx) + __expf(x.w - mx);
    if (mx > m) { s = s * __expf(m - mx) + e; m = mx; }
    else        { s += e * __expf(mx - m); }
  }
  #pragma unroll
  for (int off = 32; off; off >>= 1) {
    float m2 = __shfl_xor(m, off), s2 = __shfl_xor(s, off);
    float mm = fmaxf(m, m2);
    s = s * __expf(m - mm) + s2 * __expf(m2 - mm);
    m = mm;
  }
  __shared__ float rm[8], rs[8];
  if ((tid & 63) == 0) { rm[tid >> 6] = m; rs[tid >> 6] = s; }
  __syncthreads();
  float M = rm[0], S = rs[0];
  #pragma unroll
  for (int i = 1; i < 8; ++i) {
    float m2 = rm[i], s2 = rs[i];
    float mm = fmaxf(M, m2);
    S = S * __expf(M - mm) + s2 * __expf(m2 - mm);
    M = mm;
  }
  const float L = M + logf(S);
  for (int v = tid; v < 8000; v += 512) {
    float4 x = p4[v];
    x.x -= L; x.y -= L; x.z -= L; x.w -= L;
    p4[v] = x;
  }
}

// ---------------------------------------------------------------------------
extern "C" void kernel_launch(void* const* d_in, const int* in_sizes, int n_in,
                              void* d_out, int out_size, void* d_ws, size_t ws_size,
                              hipStream_t stream)
{
  const float* enc   = (const float*)d_in[0];
  const float* eh    = (const float*)d_in[1];
  const int*   tgt   = (const int*)  d_in[2];
  const float* emb   = (const float*)d_in[3];
  const float* Wa    = (const float*)d_in[4];
  const float* ba    = (const float*)d_in[5];
  const float* Ua    = (const float*)d_in[6];
  const float* bu    = (const float*)d_in[7];
  const float* Va    = (const float*)d_in[8];
  const float* bvp   = (const float*)d_in[9];
  const float* W_ih  = (const float*)d_in[10];
  const float* W_hh  = (const float*)d_in[11];
  const float* b_ih  = (const float*)d_in[12];
  const float* b_hh  = (const float*)d_in[13];
  const float* W_out = (const float*)d_in[14];
  const float* b_out = (const float*)d_in[15];

  float* out = (float*)d_out;
  float* ws  = (float*)d_ws;

  float* giemb = ws + WS_GIEMB;
  unsigned short* ukbf   = (unsigned short*)(ws + WS_UKBF);
  unsigned short* encbf  = (unsigned short*)(ws + WS_ENCBF);
  unsigned short* wcatbf = (unsigned short*)(ws + WS_WCATBF);
  unsigned short* wihcbf = (unsigned short*)(ws + WS_WIHCBF);
  float* bcat = ws + WS_BCAT;
  unsigned short* hbf0 = (unsigned short*)(ws + WS_HBF);
  unsigned short* hbf1 = hbf0 + BB*HH;
  float* h320 = ws + WS_H32;
  float* h321 = h320 + BB*HH;
  unsigned short* ctxbf = (unsigned short*)(ws + WS_CTXBF);
  unsigned short* hsall = (unsigned short*)(ws + WS_HSALL);
  unsigned short* wbf   = (unsigned short*)ws;   // aliases giemb+ukbf+encbf post-recurrence

  float* attn_out = out + OUT_ATT;
  float* out_ht   = out + OUT_HT;

  // ---- prep ----
  build_wcat_kernel<<<dim3(4096), dim3(256), 0, stream>>>(Wa, W_hh, ba, b_hh, wcatbf, bcat);
  build_wihc_kernel<<<dim3(3072), dim3(256), 0, stream>>>(W_ih, wihcbf);
  {
    long long n = (long long)BB*SS*HH;
    cvt_f2b_kernel<<<dim3((unsigned)(n/4/256)), dim3(256), 0, stream>>>(enc, encbf, n);
  }
  hinit_kernel<<<dim3(128), dim3(256), 0, stream>>>(eh, hbf0, h320);
  gemm_nt<0,1><<<dim3(8, 64), dim3(256), 0, stream>>>(enc, HH, Ua, HH, bu, (void*)ukbf, (long long)HH, nullptr);
  gemm_nt<1,0><<<dim3(24, 64), dim3(256), 0, stream>>>(emb, HH, W_ih, 2*HH, b_ih, (void*)giemb, (long long)H3, tgt);

  // ---- recurrence: 2 launches/step ----
  for (int t = 0; t < TT; ++t) {
    const unsigned short* hr  = (t & 1) ? hbf1 : hbf0;
    const float*          h32r = (t & 1) ? h321 : h320;
    unsigned short*       hw  = (t & 1) ? hbf0 : hbf1;
    float*                h32w = (t & 1) ? h320 : h321;
    stepA_kernel<<<dim3(64), dim3(512), 0, stream>>>(t, wcatbf, bcat, ukbf, encbf,
        Va, bvp, hr, ctxbf, attn_out);
    stepB_kernel<<<dim3(256), dim3(768), 0, stream>>>(t, wcatbf, wihcbf, bcat, giemb,
        hr, h32r, ctxbf, hw, h32w, hsall, out_ht);
  }

  // ---- output projection + log-softmax ----
  {
    long long n = (long long)VV*HH;
    cvt_f2b_kernel<<<dim3((unsigned)(n/4/256)), dim3(256), 0, stream>>>(W_out, wbf, n);
  }
  gemm_out_mfma<<<dim3(250, 32), dim3(256), 0, stream>>>(hsall, wbf, b_out, out);
  logsoftmax_kernel<<<dim3(4096), dim3(512), 0, stream>>>(out);
}

// Round 9
// 2273.878 us; speedup vs baseline: 8.3284x; 1.2832x over previous
//
#include <hip/hip_runtime.h>
#include <math.h>

#define HH 512
#define VV 32000
#define BB 64
#define SS 64
#define TT 64
#define H3 1536

// ---- workspace layout (float offsets); everything below WS_HSALL is dead
// after the recurrence, so wbf (32000*512 ushort = 8,192,000 f) aliases it. ----
#define WS_GIEMBBF 0LL          // 4096*1536 ushort = 3,145,728 f
#define WS_UKBF    3145728LL    // 4096*512 ushort
#define WS_ENCBF   4194304LL    // 4096*512 ushort
#define WS_EMBBF   5242880LL    // 4096*512 ushort
#define WS_WCATBF  6291456LL    // 2048*512 ushort
#define WS_WIHC3   6815744LL    // 1536*512 ushort (rows j*3+gate, ctx half)
#define WS_WIHE    7208960LL    // 1536*512 ushort (emb half)
#define WS_UABF    7602176LL    // 512*512 ushort
#define WS_BCAT    7733248LL    // 2048 f
#define WS_QGH     7735296LL    // 64*2048 f
#define WS_CTXBF   7866368LL    // 64*512 ushort
#define WS_H32     7882752LL    // 2 x 64*512 f
#define WS_HBF     7948288LL    // 2 x 64*512 ushort
#define WS_HSALL   8388608LL    // 4096*512 ushort (rows b*T+t)  -- LIVE after recurrence
// end 9,437,184 f = 37.7 MB

// output layout (floats)
#define OUT_HT  ((long long)BB*TT*VV)
#define OUT_ATT (OUT_HT + (long long)BB*HH)

typedef __attribute__((ext_vector_type(8))) short bf16x8;
typedef __attribute__((ext_vector_type(4))) float f32x4;

__device__ inline unsigned short f2b(float x) {
  unsigned u = __builtin_bit_cast(unsigned, x);
  unsigned r = (u + 0x7FFF + ((u >> 16) & 1)) >> 16;
  return (unsigned short)r;
}
__device__ inline float bc(unsigned u) { return __builtin_bit_cast(float, u); }
__device__ inline float b2f(unsigned short h) { return bc(((unsigned)h) << 16); }
__device__ inline float frcp(float x) { return __builtin_amdgcn_rcpf(x); }
__device__ inline float tanh_fast(float x) { return 1.f - 2.f * frcp(__expf(2.f * x) + 1.f); }
__device__ inline float sigm(float x) { return frcp(1.f + __expf(-x)); }

#define GLDS(gp, lp) __builtin_amdgcn_global_load_lds( \
    (const __attribute__((address_space(1))) void*)(gp), \
    (__attribute__((address_space(3))) void*)(lp), 16, 0, 0)

// ---------------------------------------------------------------------------
// prep kernels
// ---------------------------------------------------------------------------
__global__ __launch_bounds__(256) void build_wcat_kernel(const float* __restrict__ Wa,
    const float* __restrict__ Whh, const float* __restrict__ ba,
    const float* __restrict__ bhh, unsigned short* __restrict__ wcatbf,
    float* __restrict__ bcat)
{
  long long i = (long long)blockIdx.x * 256 + threadIdx.x;   // 2048*512
  int j = (int)(i >> 9), k = (int)(i & 511);
  float v = (j < HH) ? Wa[(long long)j*HH + k] : Whh[(long long)(j - HH)*HH + k];
  wcatbf[i] = f2b(v);
  if (i < 2048) bcat[i] = (i < HH) ? ba[i] : bhh[i - HH];
}

// wihc3bf[(j*3+g)][k] = W_ih[g*512+j][512+k]
__global__ __launch_bounds__(256) void build_wihc3_kernel(const float* __restrict__ W_ih,
    unsigned short* __restrict__ o)
{
  long long i = (long long)blockIdx.x * 256 + threadIdx.x;   // 1536*512
  int rp = (int)(i >> 9), k = (int)(i & 511);
  int j = rp / 3, g = rp - j * 3;
  o[i] = f2b(W_ih[((long long)(g*512 + j))*1024 + 512 + k]);
}

// wihebf[j][k] = W_ih[j][k]  (emb half)
__global__ __launch_bounds__(256) void build_wihe_kernel(const float* __restrict__ W_ih,
    unsigned short* __restrict__ o)
{
  long long i = (long long)blockIdx.x * 256 + threadIdx.x;   // 1536*512
  o[i] = f2b(W_ih[(long long)(i >> 9)*1024 + (i & 511)]);
}

__global__ __launch_bounds__(256) void cvt_f2b_kernel(const float* __restrict__ in,
    unsigned short* __restrict__ outp, long long n)
{
  long long i = ((long long)blockIdx.x * 256 + threadIdx.x) * 4;
  if (i >= n) return;
  float4 v = *(const float4*)(in + i);
  ushort4 r = { f2b(v.x), f2b(v.y), f2b(v.z), f2b(v.w) };
  *(ushort4*)(outp + i) = r;
}

// embbf row m = t*64+b  <-  emb[tok(b,t)]
__global__ __launch_bounds__(256) void build_embbf_kernel(const float* __restrict__ emb,
    const int* __restrict__ tgt, unsigned short* __restrict__ embbf)
{
  const int m = blockIdx.x, t = m >> 6, b = m & 63;
  const int tk = (t == 0) ? 0 : tgt[b*TT + t - 1];
  const float* src = emb + (long long)tk*HH;
  unsigned short* dst = embbf + (long long)m*HH;
  const int i = threadIdx.x;
  dst[i] = f2b(src[i]);
  dst[i + 256] = f2b(src[i + 256]);
}

__global__ __launch_bounds__(256) void hinit_kernel(const float* __restrict__ eh,
    unsigned short* __restrict__ hbf0, float* __restrict__ h320)
{
  int i = blockIdx.x * 256 + threadIdx.x;   // 32768
  float v = eh[i];
  hbf0[i] = f2b(v);
  h320[i] = v;
}

// ---------------------------------------------------------------------------
// Generic NT MFMA GEMM: C[m][n] = A[m,:512].B[n,:512] + bias[n]
// M = gridDim.y*128, N = gridDim.x*128. OUTBF: bf16 C else f32.
// ---------------------------------------------------------------------------
template<int OUTBF>
__global__ __launch_bounds__(256) void mfma_nt(const unsigned short* __restrict__ A,
    const unsigned short* __restrict__ Bw, const float* __restrict__ bias,
    void* __restrict__ Cv, long long ldc)
{
  __shared__ unsigned short As[128*32];
  __shared__ unsigned short Bs[128*32];
  const int tid = threadIdx.x;
  const int w = tid >> 6, l = tid & 63;
  const int m0 = blockIdx.y * 128, n0 = blockIdx.x * 128;
  const int wr = w >> 1, wc = w & 1;

  f32x4 acc[4][4];
  #pragma unroll
  for (int i = 0; i < 4; i++)
    #pragma unroll
    for (int j = 0; j < 4; j++) acc[i][j] = (f32x4){0.f, 0.f, 0.f, 0.f};

  const int srow = l >> 2;
  const int scol = (l & 3) * 8;

  for (int k0 = 0; k0 < HH; k0 += 32) {
    __syncthreads();
    #pragma unroll
    for (int q = 0; q < 2; ++q) {
      int r = w*32 + q*16 + srow;
      GLDS(A  + (long long)(m0 + r)*HH + k0 + scol, As + r*32 + scol);
      GLDS(Bw + (long long)(n0 + r)*HH + k0 + scol, Bs + r*32 + scol);
    }
    __syncthreads();

    bf16x8 a[4], b[4];
    #pragma unroll
    for (int mi = 0; mi < 4; mi++)
      a[mi] = *(const bf16x8*)&As[(wr*64 + mi*16 + (l & 15))*32 + (l >> 4)*8];
    #pragma unroll
    for (int ni = 0; ni < 4; ni++)
      b[ni] = *(const bf16x8*)&Bs[(wc*64 + ni*16 + (l & 15))*32 + (l >> 4)*8];
    #pragma unroll
    for (int mi = 0; mi < 4; mi++)
      #pragma unroll
      for (int ni = 0; ni < 4; ni++)
        acc[mi][ni] = __builtin_amdgcn_mfma_f32_16x16x32_bf16(a[mi], b[ni], acc[mi][ni], 0, 0, 0);
  }

  #pragma unroll
  for (int mi = 0; mi < 4; mi++) {
    #pragma unroll
    for (int ni = 0; ni < 4; ni++) {
      int col = n0 + wc*64 + ni*16 + (l & 15);
      float bb = bias[col];
      #pragma unroll
      for (int r2 = 0; r2 < 4; r2++) {
        int row = m0 + wr*64 + mi*16 + (l >> 4)*4 + r2;
        float v = acc[mi][ni][r2] + bb;
        if (OUTBF) ((unsigned short*)Cv)[(long long)row*ldc + col] = f2b(v);
        else       ((float*)Cv)[(long long)row*ldc + col] = v;
      }
    }
  }
}

// ---------------------------------------------------------------------------
// K_A: qgh[64][2048] = hbf[64][512] @ wcatbf^T + bcat.  grid 16, 256 thr.
// ---------------------------------------------------------------------------
__global__ __launch_bounds__(256) void qgh_mfma(
    const unsigned short* __restrict__ hbf_r, const unsigned short* __restrict__ wcatbf,
    const float* __restrict__ bcat, float* __restrict__ qgh)
{
  __shared__ unsigned short As[64*32];
  __shared__ unsigned short Bs[128*32];
  const int tid = threadIdx.x;
  const int w = tid >> 6, l = tid & 63;
  const int n0 = blockIdx.x * 128;
  const int wr = w >> 1, wc = w & 1;

  f32x4 acc[2][4];
  #pragma unroll
  for (int i = 0; i < 2; i++)
    #pragma unroll
    for (int j = 0; j < 4; j++) acc[i][j] = (f32x4){0.f, 0.f, 0.f, 0.f};

  const int ar = tid >> 2;          // 0..63
  const int ac8 = (tid & 3) * 8;

  for (int k0 = 0; k0 < HH; k0 += 32) {
    __syncthreads();
    GLDS(hbf_r + (long long)ar*HH + k0 + ac8, As + ar*32 + ac8);
    #pragma unroll
    for (int q = 0; q < 2; ++q) {
      int r = q*64 + ar;
      GLDS(wcatbf + (long long)(n0 + r)*HH + k0 + ac8, Bs + r*32 + ac8);
    }
    __syncthreads();

    bf16x8 a[2], b[4];
    #pragma unroll
    for (int mi = 0; mi < 2; mi++)
      a[mi] = *(const bf16x8*)&As[(wr*32 + mi*16 + (l & 15))*32 + (l >> 4)*8];
    #pragma unroll
    for (int ni = 0; ni < 4; ni++)
      b[ni] = *(const bf16x8*)&Bs[(wc*64 + ni*16 + (l & 15))*32 + (l >> 4)*8];
    #pragma unroll
    for (int mi = 0; mi < 2; mi++)
      #pragma unroll
      for (int ni = 0; ni < 4; ni++)
        acc[mi][ni] = __builtin_amdgcn_mfma_f32_16x16x32_bf16(a[mi], b[ni], acc[mi][ni], 0, 0, 0);
  }

  #pragma unroll
  for (int mi = 0; mi < 2; mi++) {
    #pragma unroll
    for (int ni = 0; ni < 4; ni++) {
      int col = n0 + wc*64 + ni*16 + (l & 15);
      float bb = bcat[col];
      #pragma unroll
      for (int r2 = 0; r2 < 4; r2++) {
        int row = wr*32 + mi*16 + (l >> 4)*4 + r2;
        qgh[(long long)row*2048 + col] = acc[mi][ni][r2] + bb;
      }
    }
  }
}

// ---------------------------------------------------------------------------
// K_B: attention for batch b = blockIdx.x. 512 thr. q from qgh.
// ---------------------------------------------------------------------------
__global__ __launch_bounds__(512) void attn_kernel(int t,
    const float* __restrict__ qgh, const unsigned short* __restrict__ ukbf,
    const unsigned short* __restrict__ encbf, const float* __restrict__ Va,
    const float* __restrict__ bvp,
    unsigned short* __restrict__ ctxbf, float* __restrict__ attn_out)
{
  const int b = blockIdx.x, tid = threadIdx.x;
  __shared__ float qs2[8][68];
  __shared__ float vsh[8][68];
  __shared__ float sc[SS], sw[SS];

  qs2[tid >> 6][tid & 63] = qgh[(long long)b*2048 + tid];
  vsh[tid >> 6][tid & 63] = Va[tid];
  __syncthreads();

  // scores: (s = tid>>3, sub = tid&7), 64 k each
  {
    const int s = tid >> 3, sub = tid & 7;
    const uint4* up = (const uint4*)(ukbf + ((long long)(b*SS + s))*512 + sub*64);
    const float* qp = &qs2[sub][0];
    const float* vp = &vsh[sub][0];
    float p_ = 0.f;
    #pragma unroll
    for (int i = 0; i < 8; ++i) {
      uint4 uv = up[i];
      int e = i*8;
      p_ = fmaf(vp[e+0], tanh_fast(qp[e+0] + bc(uv.x << 16)), p_);
      p_ = fmaf(vp[e+1], tanh_fast(qp[e+1] + bc(uv.x & 0xffff0000u)), p_);
      p_ = fmaf(vp[e+2], tanh_fast(qp[e+2] + bc(uv.y << 16)), p_);
      p_ = fmaf(vp[e+3], tanh_fast(qp[e+3] + bc(uv.y & 0xffff0000u)), p_);
      p_ = fmaf(vp[e+4], tanh_fast(qp[e+4] + bc(uv.z << 16)), p_);
      p_ = fmaf(vp[e+5], tanh_fast(qp[e+5] + bc(uv.z & 0xffff0000u)), p_);
      p_ = fmaf(vp[e+6], tanh_fast(qp[e+6] + bc(uv.w << 16)), p_);
      p_ = fmaf(vp[e+7], tanh_fast(qp[e+7] + bc(uv.w & 0xffff0000u)), p_);
    }
    p_ += __shfl_xor(p_, 1);
    p_ += __shfl_xor(p_, 2);
    p_ += __shfl_xor(p_, 4);
    if (sub == 0) sc[s] = p_ + bvp[0];
  }
  __syncthreads();

  if (tid < 64) {
    float x = sc[tid], mx = x;
    #pragma unroll
    for (int off = 32; off; off >>= 1) mx = fmaxf(mx, __shfl_xor(mx, off));
    float e = __expf(x - mx), sm = e;
    #pragma unroll
    for (int off = 32; off; off >>= 1) sm += __shfl_xor(sm, off);
    float w_ = e * frcp(sm);
    sw[tid] = w_;
    attn_out[((long long)b*TT + t)*SS + tid] = w_;
  }
  __syncthreads();

  {
    float a = 0.f;
    const unsigned short* ep = encbf + (long long)b*SS*512 + tid;
    #pragma unroll 8
    for (int s = 0; s < SS; ++s)
      a = fmaf(sw[s], b2f(ep[s*512]), a);
    ctxbf[b*512 + tid] = f2b(a);
  }
}

// ---------------------------------------------------------------------------
// K_C: gic (MFMA, gate-interleaved 96-col tile = 32 j's x 3 gates) + gates.
// grid 16 (j0 = blockIdx.x*32), 256 thr, waves 2x2 (32 rows x 48 cols).
// ---------------------------------------------------------------------------
__global__ __launch_bounds__(256) void gic_gates_mfma(int t,
    const unsigned short* __restrict__ ctxbf, const unsigned short* __restrict__ wihc3bf,
    const float* __restrict__ qgh, const unsigned short* __restrict__ giembbf,
    const float* __restrict__ h32_r, float* __restrict__ h32_w,
    unsigned short* __restrict__ hbf_w, unsigned short* __restrict__ hsall,
    float* __restrict__ out_ht)
{
  __shared__ unsigned short As[64*32];
  __shared__ unsigned short Bs[96*32];
  __shared__ float gl[64*100];            // gic tile [64][96] (+4 pad)
  const int tid = threadIdx.x;
  const int w = tid >> 6, l = tid & 63;
  const int n0 = blockIdx.x * 96, j0 = blockIdx.x * 32;
  const int wr = w >> 1, wc = w & 1;

  f32x4 acc[2][3];
  #pragma unroll
  for (int i = 0; i < 2; i++)
    #pragma unroll
    for (int j = 0; j < 3; j++) acc[i][j] = (f32x4){0.f, 0.f, 0.f, 0.f};

  const int ar = tid >> 2;
  const int ac8 = (tid & 3) * 8;

  for (int k0 = 0; k0 < HH; k0 += 32) {
    __syncthreads();
    GLDS(ctxbf + (long long)ar*HH + k0 + ac8, As + ar*32 + ac8);
    #pragma unroll
    for (int q = 0; q < 2; ++q) {
      int idx = tid + q*256;
      if (idx < 384) {
        int r = idx >> 2, c8 = (idx & 3) * 8;
        GLDS(wihc3bf + (long long)(n0 + r)*HH + k0 + c8, Bs + r*32 + c8);
      }
    }
    __syncthreads();

    bf16x8 a[2], b[3];
    #pragma unroll
    for (int mi = 0; mi < 2; mi++)
      a[mi] = *(const bf16x8*)&As[(wr*32 + mi*16 + (l & 15))*32 + (l >> 4)*8];
    #pragma unroll
    for (int ni = 0; ni < 3; ni++)
      b[ni] = *(const bf16x8*)&Bs[(wc*48 + ni*16 + (l & 15))*32 + (l >> 4)*8];
    #pragma unroll
    for (int mi = 0; mi < 2; mi++)
      #pragma unroll
      for (int ni = 0; ni < 3; ni++)
        acc[mi][ni] = __builtin_amdgcn_mfma_f32_16x16x32_bf16(a[mi], b[ni], acc[mi][ni], 0, 0, 0);
  }

  #pragma unroll
  for (int mi = 0; mi < 2; mi++)
    #pragma unroll
    for (int ni = 0; ni < 3; ni++) {
      int col = wc*48 + ni*16 + (l & 15);
      #pragma unroll
      for (int r2 = 0; r2 < 4; r2++) {
        int row = wr*32 + mi*16 + (l >> 4)*4 + r2;
        gl[row*100 + col] = acc[mi][ni][r2];
      }
    }
  __syncthreads();

  // gates: 2048 (b, jj) pairs
  for (int i = tid; i < 2048; i += 256) {
    const int b = i >> 5, jj = i & 31, j = j0 + jj;
    float gr = gl[b*100 + jj*3 + 0];
    float gz = gl[b*100 + jj*3 + 1];
    float gn = gl[b*100 + jj*3 + 2];
    const float* qg = qgh + (long long)b*2048 + 512;
    float ghr = qg[j], ghz = qg[512 + j], ghn = qg[1024 + j];
    const long long gb = ((long long)t*BB + b)*H3 + j;
    float gir = b2f(giembbf[gb]);
    float giz = b2f(giembbf[gb + 512]);
    float gin = b2f(giembbf[gb + 1024]);
    float r = sigm(gir + gr + ghr);
    float z = sigm(giz + gz + ghz);
    float n = tanh_fast(gin + gn + r * ghn);
    float hold = h32_r[b*512 + j];
    float hn = (1.f - z) * n + z * hold;
    h32_w[b*512 + j] = hn;
    unsigned short hb = f2b(hn);
    hbf_w[b*512 + j] = hb;
    hsall[((long long)b*TT + t)*512 + j] = hb;
    if (t == TT - 1) out_ht[b*512 + j] = hn;
  }
}

// ---------------------------------------------------------------------------
// In-place log-softmax over rows of V=32000, 1024 thr, float4
// ---------------------------------------------------------------------------
__global__ __launch_bounds__(1024) void logsoftmax_kernel(float* __restrict__ lp)
{
  float4* p4 = (float4*)(lp + (long long)blockIdx.x * VV);
  const int tid = threadIdx.x;
  float m = -1e30f, s = 0.f;
  for (int v = tid; v < 8000; v += 1024) {
    float4 x = p4[v];
    float mx = fmaxf(fmaxf(x.x, x.y), fmaxf(x.z, x.w));
    float e = __expf(x.x - mx) + __expf(x.y - mx) + __expf(x.z - mx) + __expf(x.w - mx);
    if (mx > m) { s = s * __expf(m - mx) + e; m = mx; }
    else        { s += e * __expf(mx - m); }
  }
  #pragma unroll
  for (int off = 32; off; off >>= 1) {
    float m2 = __shfl_xor(m, off), s2 = __shfl_xor(s, off);
    float mm = fmaxf(m, m2);
    s = s * __expf(m - mm) + s2 * __expf(m2 - mm);
    m = mm;
  }
  __shared__ float rm[16], rs[16];
  if ((tid & 63) == 0) { rm[tid >> 6] = m; rs[tid >> 6] = s; }
  __syncthreads();
  float M = rm[0], S = rs[0];
  #pragma unroll
  for (int i = 1; i < 16; ++i) {
    float m2 = rm[i], s2 = rs[i];
    float mm = fmaxf(M, m2);
    S = S * __expf(M - mm) + s2 * __expf(m2 - mm);
    M = mm;
  }
  const float L = M + logf(S);
  for (int v = tid; v < 8000; v += 1024) {
    float4 x = p4[v];
    x.x -= L; x.y -= L; x.z -= L; x.w -= L;
    p4[v] = x;
  }
}

// ---------------------------------------------------------------------------
extern "C" void kernel_launch(void* const* d_in, const int* in_sizes, int n_in,
                              void* d_out, int out_size, void* d_ws, size_t ws_size,
                              hipStream_t stream)
{
  const float* enc   = (const float*)d_in[0];
  const float* eh    = (const float*)d_in[1];
  const int*   tgt   = (const int*)  d_in[2];
  const float* emb   = (const float*)d_in[3];
  const float* Wa    = (const float*)d_in[4];
  const float* ba    = (const float*)d_in[5];
  const float* Ua    = (const float*)d_in[6];
  const float* bu    = (const float*)d_in[7];
  const float* Va    = (const float*)d_in[8];
  const float* bvp   = (const float*)d_in[9];
  const float* W_ih  = (const float*)d_in[10];
  const float* W_hh  = (const float*)d_in[11];
  const float* b_ih  = (const float*)d_in[12];
  const float* b_hh  = (const float*)d_in[13];
  const float* W_out = (const float*)d_in[14];
  const float* b_out = (const float*)d_in[15];

  float* out = (float*)d_out;
  float* ws  = (float*)d_ws;

  unsigned short* giembbf = (unsigned short*)(ws + WS_GIEMBBF);
  unsigned short* ukbf    = (unsigned short*)(ws + WS_UKBF);
  unsigned short* encbf   = (unsigned short*)(ws + WS_ENCBF);
  unsigned short* embbf   = (unsigned short*)(ws + WS_EMBBF);
  unsigned short* wcatbf  = (unsigned short*)(ws + WS_WCATBF);
  unsigned short* wihc3bf = (unsigned short*)(ws + WS_WIHC3);
  unsigned short* wihebf  = (unsigned short*)(ws + WS_WIHE);
  unsigned short* uabf    = (unsigned short*)(ws + WS_UABF);
  float* bcat = ws + WS_BCAT;
  float* qgh  = ws + WS_QGH;
  unsigned short* ctxbf = (unsigned short*)(ws + WS_CTXBF);
  float* h320 = ws + WS_H32;
  float* h321 = h320 + BB*HH;
  unsigned short* hbf0 = (unsigned short*)(ws + WS_HBF);
  unsigned short* hbf1 = hbf0 + BB*HH;
  unsigned short* hsall = (unsigned short*)(ws + WS_HSALL);
  unsigned short* wbf   = (unsigned short*)ws;   // aliases dead region post-recurrence

  float* attn_out = out + OUT_ATT;
  float* out_ht   = out + OUT_HT;

  // ---- prep ----
  build_wcat_kernel<<<dim3(4096), dim3(256), 0, stream>>>(Wa, W_hh, ba, b_hh, wcatbf, bcat);
  build_wihc3_kernel<<<dim3(3072), dim3(256), 0, stream>>>(W_ih, wihc3bf);
  build_wihe_kernel<<<dim3(3072), dim3(256), 0, stream>>>(W_ih, wihebf);
  cvt_f2b_kernel<<<dim3(256), dim3(256), 0, stream>>>(Ua, uabf, (long long)HH*HH);
  cvt_f2b_kernel<<<dim3(2048), dim3(256), 0, stream>>>(enc, encbf, (long long)BB*SS*HH);
  build_embbf_kernel<<<dim3(4096), dim3(256), 0, stream>>>(emb, tgt, embbf);
  hinit_kernel<<<dim3(128), dim3(256), 0, stream>>>(eh, hbf0, h320);

  // Uk (bf16 out) and GiEmb (bf16 out) via MFMA
  mfma_nt<1><<<dim3(4, 32), dim3(256), 0, stream>>>(encbf, uabf, bu, (void*)ukbf, (long long)HH);
  mfma_nt<1><<<dim3(12, 32), dim3(256), 0, stream>>>(embbf, wihebf, b_ih, (void*)giembbf, (long long)H3);

  // ---- recurrence: 3 launches/step ----
  for (int t = 0; t < TT; ++t) {
    const unsigned short* hr  = (t & 1) ? hbf1 : hbf0;
    const float*          h32r = (t & 1) ? h321 : h320;
    unsigned short*       hw  = (t & 1) ? hbf0 : hbf1;
    float*                h32w = (t & 1) ? h320 : h321;
    qgh_mfma<<<dim3(16), dim3(256), 0, stream>>>(hr, wcatbf, bcat, qgh);
    attn_kernel<<<dim3(64), dim3(512), 0, stream>>>(t, qgh, ukbf, encbf, Va, bvp, ctxbf, attn_out);
    gic_gates_mfma<<<dim3(16), dim3(256), 0, stream>>>(t, ctxbf, wihc3bf, qgh, giembbf,
        h32r, h32w, hw, hsall, out_ht);
  }

  // ---- output projection + log-softmax ----
  cvt_f2b_kernel<<<dim3(16000), dim3(256), 0, stream>>>(W_out, wbf, (long long)VV*HH);
  mfma_nt<0><<<dim3(250, 32), dim3(256), 0, stream>>>(hsall, wbf, b_out, (void*)out, (long long)VV);
  logsoftmax_kernel<<<dim3(4096), dim3(1024), 0, stream>>>(out);
}